// Round 1
// baseline (3182.911 us; speedup 1.0000x reference)
//
#include <hip/hip_runtime.h>
#include <cstddef>

// ---------------------------------------------------------------------------
// GCNnet: mlp1(xd), mlp2(xm) -> concat -> GCNConv -> relu -> edge dot scores
// fp32 baseline. Edge indices may be int32 or int64 (detected at runtime).
// ---------------------------------------------------------------------------

__device__ __forceinline__ int eidx(const void* p, int f64, long long i) {
  if (f64) return (int)((const long long*)p)[i];
  return ((const int*)p)[i];
}

// Detect int64 vs int32 edge buffers: values < 2^17, so int64 => odd words 0.
__global__ void detect_kernel(const void* __restrict__ ei,
                              const void* __restrict__ eit,
                              int* __restrict__ flags) {
  const unsigned* a = (const unsigned*)ei;
  const unsigned* b = (const unsigned*)eit;
  int f1 = 1, f2 = 1;
  for (int i = 0; i < 64; ++i) {
    if (a[2 * i + 1] != 0u) f1 = 0;
    if (b[2 * i + 1] != 0u) f2 = 0;
  }
  flags[0] = f1;
  flags[1] = f2;
}

__global__ void init_deg_kernel(float* __restrict__ deg, int n) {
  int i = blockIdx.x * blockDim.x + threadIdx.x;
  if (i < n) deg[i] = 1.0f;
}

__global__ void deg_kernel(const void* __restrict__ ei,
                           const int* __restrict__ flags,
                           float* __restrict__ deg, int E) {
  int e = blockIdx.x * blockDim.x + threadIdx.x;
  if (e >= E) return;
  int d = eidx(ei, flags[0], (long long)E + e);
  unsafeAtomicAdd(&deg[d], 1.0f);
}

__global__ void rsqrt_kernel(float* __restrict__ deg, int n) {
  int i = blockIdx.x * blockDim.x + threadIdx.x;
  if (i < n) deg[i] = rsqrtf(deg[i]);
}

// C[M,128] = X[M,K] @ W[K,128]; RELU: C = relu(C + bias).
// GCN: Y = C (raw), accOut = C * norm[row]^2 (self-loop-seeded accumulator).
template <int K, bool RELU, bool GCN>
__global__ __launch_bounds__(256) void gemm128_kernel(
    const float* __restrict__ X, const float* __restrict__ W,
    const float* __restrict__ bias, float* __restrict__ Y,
    float* __restrict__ accOut, const float* __restrict__ norm, int M) {
  constexpr int BM = 128, BK = 32;
  __shared__ float XsT[BK][BM + 4];   // transposed X tile
  __shared__ float Ws[BK][128 + 4];   // W tile

  const int tid = threadIdx.x;            // 256 threads
  const int tx = tid & 15, ty = tid >> 4; // 16 x 16
  const int m0 = blockIdx.x * BM;

  float acc[8][8];
#pragma unroll
  for (int r = 0; r < 8; ++r)
#pragma unroll
    for (int c = 0; c < 8; ++c) acc[r][c] = 0.0f;

  for (int k0 = 0; k0 < K; k0 += BK) {
    // Stage X tile (128 rows x 32 k), transposed into LDS. 4 float4 / thread.
#pragma unroll
    for (int p = 0; p < 4; ++p) {
      int idx = p * 256 + tid;     // 0..1023
      int row = idx >> 3;          // 0..127
      int c4 = (idx & 7) * 4;      // k offset
      float4 v = make_float4(0.f, 0.f, 0.f, 0.f);
      int grow = m0 + row;
      if (grow < M) v = *(const float4*)&X[(size_t)grow * K + k0 + c4];
      XsT[c4 + 0][row] = v.x;
      XsT[c4 + 1][row] = v.y;
      XsT[c4 + 2][row] = v.z;
      XsT[c4 + 3][row] = v.w;
    }
    // Stage W tile (32 k x 128 n). 4 float4 / thread.
#pragma unroll
    for (int p = 0; p < 4; ++p) {
      int idx = p * 256 + tid;
      int kk = idx >> 5;           // 0..31
      int n4 = (idx & 31) * 4;
      float4 v = *(const float4*)&W[(size_t)(k0 + kk) * 128 + n4];
      *(float4*)&Ws[kk][n4] = v;
    }
    __syncthreads();

#pragma unroll
    for (int k = 0; k < BK; ++k) {
      float4 a0 = *(const float4*)&XsT[k][ty * 4];
      float4 a1 = *(const float4*)&XsT[k][64 + ty * 4];
      float4 b0 = *(const float4*)&Ws[k][tx * 4];
      float4 b1 = *(const float4*)&Ws[k][64 + tx * 4];
      float a[8] = {a0.x, a0.y, a0.z, a0.w, a1.x, a1.y, a1.z, a1.w};
      float b[8] = {b0.x, b0.y, b0.z, b0.w, b1.x, b1.y, b1.z, b1.w};
#pragma unroll
      for (int r = 0; r < 8; ++r)
#pragma unroll
        for (int c = 0; c < 8; ++c) acc[r][c] += a[r] * b[c];
    }
    __syncthreads();
  }

  // Epilogue
#pragma unroll
  for (int r = 0; r < 8; ++r) {
    int row = (r < 4) ? (ty * 4 + r) : (64 + ty * 4 + (r - 4));
    int grow = m0 + row;
    if (grow >= M) continue;
    float nw = 0.0f;
    if (GCN) {
      float nv = norm[grow];
      nw = nv * nv;
    }
#pragma unroll
    for (int hf = 0; hf < 2; ++hf) {
      int col0 = hf * 64 + tx * 4;
      float4 v;
      v.x = acc[r][hf * 4 + 0];
      v.y = acc[r][hf * 4 + 1];
      v.z = acc[r][hf * 4 + 2];
      v.w = acc[r][hf * 4 + 3];
      if (RELU) {
        float4 b = *(const float4*)&bias[col0];
        v.x = fmaxf(v.x + b.x, 0.0f);
        v.y = fmaxf(v.y + b.y, 0.0f);
        v.z = fmaxf(v.z + b.z, 0.0f);
        v.w = fmaxf(v.w + b.w, 0.0f);
      }
      *(float4*)&Y[(size_t)grow * 128 + col0] = v;
      if (GCN) {
        float4 s;
        s.x = v.x * nw;
        s.y = v.y * nw;
        s.z = v.z * nw;
        s.w = v.w * nw;
        *(float4*)&accOut[(size_t)grow * 128 + col0] = s;
      }
    }
  }
}

// Edge aggregation: acc[dst] += h2[src] * norm[src]*norm[dst]. 32 lanes/edge.
__global__ void agg_kernel(const float* __restrict__ h2,
                           const float* __restrict__ norm,
                           float* __restrict__ acc,
                           const void* __restrict__ ei,
                           const int* __restrict__ flags, int E) {
  int t = blockIdx.x * blockDim.x + threadIdx.x;
  int e = t >> 5;
  if (e >= E) return;
  int l = t & 31;
  int f = flags[0];
  int s = eidx(ei, f, e);
  int d = eidx(ei, f, (long long)E + e);
  float coef = norm[s] * norm[d];
  float4 v = *(const float4*)&h2[(size_t)s * 128 + l * 4];
  float* dst = &acc[(size_t)d * 128 + l * 4];
  unsafeAtomicAdd(dst + 0, v.x * coef);
  unsafeAtomicAdd(dst + 1, v.y * coef);
  unsafeAtomicAdd(dst + 2, v.z * coef);
  unsafeAtomicAdd(dst + 3, v.w * coef);
}

// x2 = relu(acc + bg), in place. One float4 per thread.
__global__ void finalize_kernel(float* __restrict__ acc,
                                const float* __restrict__ bg, int n32) {
  int t = blockIdx.x * blockDim.x + threadIdx.x;
  if (t >= n32) return;
  int c4 = (t & 31) * 4;
  float4 v = *(float4*)&acc[(size_t)t * 4];
  float4 b = *(const float4*)&bg[c4];
  v.x = fmaxf(v.x + b.x, 0.0f);
  v.y = fmaxf(v.y + b.y, 0.0f);
  v.z = fmaxf(v.z + b.z, 0.0f);
  v.w = fmaxf(v.w + b.w, 0.0f);
  *(float4*)&acc[(size_t)t * 4] = v;
}

// scores[e] = dot(x2[src], x2[dst]) over 128 ch. 32 lanes/edge.
__global__ void score_kernel(const float* __restrict__ x2,
                             const void* __restrict__ eit,
                             const int* __restrict__ flags,
                             float* __restrict__ out, int ET) {
  int t = blockIdx.x * blockDim.x + threadIdx.x;
  int e = t >> 5;
  if (e >= ET) return;
  int l = t & 31;
  int f = flags[1];
  int s = eidx(eit, f, e);
  int d = eidx(eit, f, (long long)ET + e);
  float4 a = *(const float4*)&x2[(size_t)s * 128 + l * 4];
  float4 b = *(const float4*)&x2[(size_t)d * 128 + l * 4];
  float p = a.x * b.x + a.y * b.y + a.z * b.z + a.w * b.w;
  p += __shfl_xor(p, 16);
  p += __shfl_xor(p, 8);
  p += __shfl_xor(p, 4);
  p += __shfl_xor(p, 2);
  p += __shfl_xor(p, 1);
  if (l == 0) out[e] = p;
}

extern "C" void kernel_launch(void* const* d_in, const int* in_sizes, int n_in,
                              void* d_out, int out_size, void* d_ws,
                              size_t ws_size, hipStream_t stream) {
  const float* xd = (const float*)d_in[0];
  const float* xm = (const float*)d_in[1];
  const void* ei = d_in[2];
  const void* eit = d_in[3];
  const float* W1 = (const float*)d_in[4];
  const float* b1 = (const float*)d_in[5];
  const float* W2 = (const float*)d_in[6];
  const float* b2 = (const float*)d_in[7];
  const float* Wg = (const float*)d_in[8];
  const float* bg = (const float*)d_in[9];

  const int ND = in_sizes[0] / 256;
  const int NM = in_sizes[1] / 256;
  const int N = ND + NM;
  const int E = in_sizes[2] / 2;
  const int ET = in_sizes[3] / 2;

  float* h = (float*)d_ws;                  // N*128 (MLP out; later acc/x2)
  float* h2 = h + (size_t)N * 128;          // N*128 (GCN matmul out)
  float* deg = h2 + (size_t)N * 128;        // N (deg -> norm)
  int* flags = (int*)(deg + (((size_t)N + 255) & ~(size_t)255));

  float* out = (float*)d_out;

  detect_kernel<<<1, 1, 0, stream>>>(ei, eit, flags);
  init_deg_kernel<<<(N + 255) / 256, 256, 0, stream>>>(deg, N);
  deg_kernel<<<(E + 255) / 256, 256, 0, stream>>>(ei, flags, deg, E);
  rsqrt_kernel<<<(N + 255) / 256, 256, 0, stream>>>(deg, N);

  // MLPs -> h (concat order: xd rows first, then xm)
  gemm128_kernel<256, true, false><<<(ND + 127) / 128, 256, 0, stream>>>(
      xd, W1, b1, h, nullptr, nullptr, ND);
  gemm128_kernel<256, true, false><<<(NM + 127) / 128, 256, 0, stream>>>(
      xm, W2, b2, h + (size_t)ND * 128, nullptr, nullptr, NM);

  // GCN matmul: h2 = h @ Wg; acc (aliases h) = h2 * norm^2 (self-loop term).
  gemm128_kernel<128, false, true><<<(N + 127) / 128, 256, 0, stream>>>(
      h, Wg, nullptr, h2, h, deg, N);

  // Edge aggregation into acc (= h buffer).
  {
    long long tt = (long long)E * 32;
    agg_kernel<<<(unsigned)((tt + 255) / 256), 256, 0, stream>>>(h2, deg, h, ei,
                                                                 flags, E);
  }

  // x2 = relu(acc + bg)
  finalize_kernel<<<(N * 32 + 255) / 256, 256, 0, stream>>>(h, bg, N * 32);

  // scores
  {
    long long tt = (long long)ET * 32;
    score_kernel<<<(unsigned)((tt + 255) / 256), 256, 0, stream>>>(h, eit, flags,
                                                                   out, ET);
  }
}

// Round 2
// 702.144 us; speedup vs baseline: 4.5331x; 4.5331x over previous
//
#include <hip/hip_runtime.h>
#include <cstddef>

// ---------------------------------------------------------------------------
// GCNnet: mlp1(xd), mlp2(xm) -> concat -> GCNConv -> relu -> edge dot scores
// Round 2: replace fp32 atomic scatter-aggregation (2677 us, atomic-bound)
// with counting-sort-by-dst + register gather-sum (no fp atomics).
// ---------------------------------------------------------------------------

__device__ __forceinline__ int eidx(const void* p, int f64, long long i) {
  if (f64) return (int)((const long long*)p)[i];
  return ((const int*)p)[i];
}

// Detect int64 vs int32 edge buffers: values < 2^17, so int64 => odd words 0.
__global__ void detect_kernel(const void* __restrict__ ei,
                              const void* __restrict__ eit,
                              int* __restrict__ flags) {
  const unsigned* a = (const unsigned*)ei;
  const unsigned* b = (const unsigned*)eit;
  int f1 = 1, f2 = 1;
  for (int i = 0; i < 64; ++i) {
    if (a[2 * i + 1] != 0u) f1 = 0;
    if (b[2 * i + 1] != 0u) f2 = 0;
  }
  flags[0] = f1;
  flags[1] = f2;
}

__global__ void zero_int_kernel(int* __restrict__ p, int n) {
  int i = blockIdx.x * blockDim.x + threadIdx.x;
  if (i < n) p[i] = 0;
}

// Histogram of destination nodes (int atomics, fast at L2).
__global__ void hist_kernel(const void* __restrict__ ei,
                            const int* __restrict__ flags,
                            int* __restrict__ count, int E) {
  int e = blockIdx.x * blockDim.x + threadIdx.x;
  if (e >= E) return;
  int d = eidx(ei, flags[0], (long long)E + e);
  atomicAdd(&count[d], 1);
}

// norm[i] = rsqrt(deg) with deg = count[i] + 1 (self-loop).
__global__ void norm_kernel(const int* __restrict__ count,
                            float* __restrict__ norm, int n) {
  int i = blockIdx.x * blockDim.x + threadIdx.x;
  if (i < n) norm[i] = rsqrtf((float)count[i] + 1.0f);
}

// Two-level exclusive scan: scan1 (per-block) -> scan2 (block sums) -> scan3.
__global__ __launch_bounds__(256) void scan1_kernel(const int* __restrict__ count,
                                                    int* __restrict__ offsets,
                                                    int* __restrict__ bsum, int n) {
  __shared__ int s[256];
  int t = threadIdx.x;
  int i = blockIdx.x * 256 + t;
  int v = (i < n) ? count[i] : 0;
  s[t] = v;
  __syncthreads();
#pragma unroll
  for (int off = 1; off < 256; off <<= 1) {
    int x = (t >= off) ? s[t - off] : 0;
    __syncthreads();
    s[t] += x;
    __syncthreads();
  }
  if (i < n) offsets[i] = s[t] - v;  // exclusive
  if (t == 255) bsum[blockIdx.x] = s[255];
}

__global__ __launch_bounds__(512) void scan2_kernel(int* __restrict__ bsum, int nb) {
  __shared__ int s[512];
  int t = threadIdx.x;
  int v = (t < nb) ? bsum[t] : 0;
  s[t] = v;
  __syncthreads();
#pragma unroll
  for (int off = 1; off < 512; off <<= 1) {
    int x = (t >= off) ? s[t - off] : 0;
    __syncthreads();
    s[t] += x;
    __syncthreads();
  }
  if (t < nb) bsum[t] = s[t] - v;  // exclusive
}

__global__ void scan3_kernel(int* __restrict__ offsets, int* __restrict__ cursor,
                             const int* __restrict__ bsum, int n) {
  int i = blockIdx.x * blockDim.x + threadIdx.x;
  if (i < n) {
    int o = offsets[i] + bsum[blockIdx.x * 256 / 256 == 0 ? 0 : 0];  // placeholder
    (void)o;
  }
}

// (real scan3 below — keep grid mapping identical to scan1)
__global__ __launch_bounds__(256) void scan3b_kernel(int* __restrict__ offsets,
                                                     int* __restrict__ cursor,
                                                     const int* __restrict__ bsum,
                                                     int n) {
  int i = blockIdx.x * 256 + threadIdx.x;
  if (i < n) {
    int o = offsets[i] + bsum[blockIdx.x];
    offsets[i] = o;
    cursor[i] = o;
  }
}

// Scatter edge src indices into dst-sorted order.
__global__ void scatter_kernel(const void* __restrict__ ei,
                               const int* __restrict__ flags,
                               int* __restrict__ cursor,
                               int* __restrict__ sorted_src, int E) {
  int e = blockIdx.x * blockDim.x + threadIdx.x;
  if (e >= E) return;
  int f = flags[0];
  int s = eidx(ei, f, e);
  int d = eidx(ei, f, (long long)E + e);
  int pos = atomicAdd(&cursor[d], 1);
  sorted_src[pos] = s;
}

// C[M,128] = X[M,K] @ W[K,128]; RELU: C = relu(C + bias).
// GCN: Y = C (raw), accOut = C * norm[row]^2 (self-loop-seeded accumulator).
template <int K, bool RELU, bool GCN>
__global__ __launch_bounds__(256) void gemm128_kernel(
    const float* __restrict__ X, const float* __restrict__ W,
    const float* __restrict__ bias, float* __restrict__ Y,
    float* __restrict__ accOut, const float* __restrict__ norm, int M) {
  constexpr int BM = 128, BK = 32;
  __shared__ float XsT[BK][BM + 4];
  __shared__ float Ws[BK][128 + 4];

  const int tid = threadIdx.x;
  const int tx = tid & 15, ty = tid >> 4;
  const int m0 = blockIdx.x * BM;

  float acc[8][8];
#pragma unroll
  for (int r = 0; r < 8; ++r)
#pragma unroll
    for (int c = 0; c < 8; ++c) acc[r][c] = 0.0f;

  for (int k0 = 0; k0 < K; k0 += BK) {
#pragma unroll
    for (int p = 0; p < 4; ++p) {
      int idx = p * 256 + tid;
      int row = idx >> 3;
      int c4 = (idx & 7) * 4;
      float4 v = make_float4(0.f, 0.f, 0.f, 0.f);
      int grow = m0 + row;
      if (grow < M) v = *(const float4*)&X[(size_t)grow * K + k0 + c4];
      XsT[c4 + 0][row] = v.x;
      XsT[c4 + 1][row] = v.y;
      XsT[c4 + 2][row] = v.z;
      XsT[c4 + 3][row] = v.w;
    }
#pragma unroll
    for (int p = 0; p < 4; ++p) {
      int idx = p * 256 + tid;
      int kk = idx >> 5;
      int n4 = (idx & 31) * 4;
      float4 v = *(const float4*)&W[(size_t)(k0 + kk) * 128 + n4];
      *(float4*)&Ws[kk][n4] = v;
    }
    __syncthreads();

#pragma unroll
    for (int k = 0; k < BK; ++k) {
      float4 a0 = *(const float4*)&XsT[k][ty * 4];
      float4 a1 = *(const float4*)&XsT[k][64 + ty * 4];
      float4 b0 = *(const float4*)&Ws[k][tx * 4];
      float4 b1 = *(const float4*)&Ws[k][64 + tx * 4];
      float a[8] = {a0.x, a0.y, a0.z, a0.w, a1.x, a1.y, a1.z, a1.w};
      float b[8] = {b0.x, b0.y, b0.z, b0.w, b1.x, b1.y, b1.z, b1.w};
#pragma unroll
      for (int r = 0; r < 8; ++r)
#pragma unroll
        for (int c = 0; c < 8; ++c) acc[r][c] += a[r] * b[c];
    }
    __syncthreads();
  }

#pragma unroll
  for (int r = 0; r < 8; ++r) {
    int row = (r < 4) ? (ty * 4 + r) : (64 + ty * 4 + (r - 4));
    int grow = m0 + row;
    if (grow >= M) continue;
    float nw = 0.0f;
    if (GCN) {
      float nv = norm[grow];
      nw = nv * nv;
    }
#pragma unroll
    for (int hf = 0; hf < 2; ++hf) {
      int col0 = hf * 64 + tx * 4;
      float4 v;
      v.x = acc[r][hf * 4 + 0];
      v.y = acc[r][hf * 4 + 1];
      v.z = acc[r][hf * 4 + 2];
      v.w = acc[r][hf * 4 + 3];
      if (RELU) {
        float4 b = *(const float4*)&bias[col0];
        v.x = fmaxf(v.x + b.x, 0.0f);
        v.y = fmaxf(v.y + b.y, 0.0f);
        v.z = fmaxf(v.z + b.z, 0.0f);
        v.w = fmaxf(v.w + b.w, 0.0f);
      }
      *(float4*)&Y[(size_t)grow * 128 + col0] = v;
      if (GCN) {
        float4 s;
        s.x = v.x * nw;
        s.y = v.y * nw;
        s.z = v.z * nw;
        s.w = v.w * nw;
        *(float4*)&accOut[(size_t)grow * 128 + col0] = s;
      }
    }
  }
}

// Gather-aggregate: for each dst node (32 lanes), sum coef*h2[src] over its
// sorted incoming edges, seeded with the self-loop term in accSelf; then
// bias + relu, write x2 in place of accSelf. No fp atomics.
__global__ __launch_bounds__(256) void gather_agg_kernel(
    const float* __restrict__ h2, const float* __restrict__ norm,
    const int* __restrict__ offsets, const int* __restrict__ count,
    const int* __restrict__ sorted_src, const float* __restrict__ bg,
    float* __restrict__ accSelf, int N) {
  int t = blockIdx.x * blockDim.x + threadIdx.x;
  int node = t >> 5;
  if (node >= N) return;
  int l = t & 31;

  float nd = norm[node];
  int start = offsets[node];
  int len = count[node];

  float4 a = *(const float4*)&accSelf[(size_t)node * 128 + l * 4];

  int j = 0;
  for (; j + 2 <= len; j += 2) {
    int s0 = sorted_src[start + j];
    int s1 = sorted_src[start + j + 1];
    float c0 = norm[s0] * nd;
    float c1 = norm[s1] * nd;
    float4 v0 = *(const float4*)&h2[(size_t)s0 * 128 + l * 4];
    float4 v1 = *(const float4*)&h2[(size_t)s1 * 128 + l * 4];
    a.x += c0 * v0.x + c1 * v1.x;
    a.y += c0 * v0.y + c1 * v1.y;
    a.z += c0 * v0.z + c1 * v1.z;
    a.w += c0 * v0.w + c1 * v1.w;
  }
  if (j < len) {
    int s0 = sorted_src[start + j];
    float c0 = norm[s0] * nd;
    float4 v0 = *(const float4*)&h2[(size_t)s0 * 128 + l * 4];
    a.x += c0 * v0.x;
    a.y += c0 * v0.y;
    a.z += c0 * v0.z;
    a.w += c0 * v0.w;
  }

  float4 b = *(const float4*)&bg[l * 4];
  a.x = fmaxf(a.x + b.x, 0.0f);
  a.y = fmaxf(a.y + b.y, 0.0f);
  a.z = fmaxf(a.z + b.z, 0.0f);
  a.w = fmaxf(a.w + b.w, 0.0f);
  *(float4*)&accSelf[(size_t)node * 128 + l * 4] = a;
}

// ---- fallback (round-1 atomic path) -----------------------------------
__global__ void init_deg_kernel(float* __restrict__ deg, int n) {
  int i = blockIdx.x * blockDim.x + threadIdx.x;
  if (i < n) deg[i] = 1.0f;
}
__global__ void deg_kernel(const void* __restrict__ ei,
                           const int* __restrict__ flags,
                           float* __restrict__ deg, int E) {
  int e = blockIdx.x * blockDim.x + threadIdx.x;
  if (e >= E) return;
  int d = eidx(ei, flags[0], (long long)E + e);
  unsafeAtomicAdd(&deg[d], 1.0f);
}
__global__ void rsqrt_kernel(float* __restrict__ deg, int n) {
  int i = blockIdx.x * blockDim.x + threadIdx.x;
  if (i < n) deg[i] = rsqrtf(deg[i]);
}
__global__ void agg_kernel(const float* __restrict__ h2,
                           const float* __restrict__ norm,
                           float* __restrict__ acc,
                           const void* __restrict__ ei,
                           const int* __restrict__ flags, int E) {
  int t = blockIdx.x * blockDim.x + threadIdx.x;
  int e = t >> 5;
  if (e >= E) return;
  int l = t & 31;
  int f = flags[0];
  int s = eidx(ei, f, e);
  int d = eidx(ei, f, (long long)E + e);
  float coef = norm[s] * norm[d];
  float4 v = *(const float4*)&h2[(size_t)s * 128 + l * 4];
  float* dst = &acc[(size_t)d * 128 + l * 4];
  unsafeAtomicAdd(dst + 0, v.x * coef);
  unsafeAtomicAdd(dst + 1, v.y * coef);
  unsafeAtomicAdd(dst + 2, v.z * coef);
  unsafeAtomicAdd(dst + 3, v.w * coef);
}
__global__ void finalize_kernel(float* __restrict__ acc,
                                const float* __restrict__ bg, int n32) {
  int t = blockIdx.x * blockDim.x + threadIdx.x;
  if (t >= n32) return;
  int c4 = (t & 31) * 4;
  float4 v = *(float4*)&acc[(size_t)t * 4];
  float4 b = *(const float4*)&bg[c4];
  v.x = fmaxf(v.x + b.x, 0.0f);
  v.y = fmaxf(v.y + b.y, 0.0f);
  v.z = fmaxf(v.z + b.z, 0.0f);
  v.w = fmaxf(v.w + b.w, 0.0f);
  *(float4*)&acc[(size_t)t * 4] = v;
}
// -----------------------------------------------------------------------

// scores[e] = dot(x2[src], x2[dst]) over 128 ch. 32 lanes/edge.
__global__ void score_kernel(const float* __restrict__ x2,
                             const void* __restrict__ eit,
                             const int* __restrict__ flags,
                             float* __restrict__ out, int ET) {
  int t = blockIdx.x * blockDim.x + threadIdx.x;
  int e = t >> 5;
  if (e >= ET) return;
  int l = t & 31;
  int f = flags[1];
  int s = eidx(eit, f, e);
  int d = eidx(eit, f, (long long)ET + e);
  float4 a = *(const float4*)&x2[(size_t)s * 128 + l * 4];
  float4 b = *(const float4*)&x2[(size_t)d * 128 + l * 4];
  float p = a.x * b.x + a.y * b.y + a.z * b.z + a.w * b.w;
  p += __shfl_xor(p, 16);
  p += __shfl_xor(p, 8);
  p += __shfl_xor(p, 4);
  p += __shfl_xor(p, 2);
  p += __shfl_xor(p, 1);
  if (l == 0) out[e] = p;
}

extern "C" void kernel_launch(void* const* d_in, const int* in_sizes, int n_in,
                              void* d_out, int out_size, void* d_ws,
                              size_t ws_size, hipStream_t stream) {
  const float* xd = (const float*)d_in[0];
  const float* xm = (const float*)d_in[1];
  const void* ei = d_in[2];
  const void* eit = d_in[3];
  const float* W1 = (const float*)d_in[4];
  const float* b1 = (const float*)d_in[5];
  const float* W2 = (const float*)d_in[6];
  const float* b2 = (const float*)d_in[7];
  const float* Wg = (const float*)d_in[8];
  const float* bg = (const float*)d_in[9];

  const int ND = in_sizes[0] / 256;
  const int NM = in_sizes[1] / 256;
  const int N = ND + NM;
  const int E = in_sizes[2] / 2;
  const int ET = in_sizes[3] / 2;

  float* out = (float*)d_out;

  // Workspace layout
  float* h = (float*)d_ws;                  // N*128 (MLP out -> acc -> x2)
  float* h2 = h + (size_t)N * 128;          // N*128
  float* norm = h2 + (size_t)N * 128;       // N
  int* count = (int*)(norm + N);            // N
  int* offsets = count + N;                 // N
  int* cursor = offsets + N;                // N
  int* bsum = cursor + N;                   // 1024
  int* sorted_src = bsum + 1024;            // E
  int* flags = sorted_src + E;              // 2
  size_t needed = (size_t)((char*)(flags + 16) - (char*)d_ws);

  const int nb = (N + 255) / 256;

  detect_kernel<<<1, 1, 0, stream>>>(ei, eit, flags);

  if (ws_size >= needed) {
    // --- sort-based path ---
    zero_int_kernel<<<nb, 256, 0, stream>>>(count, N);
    hist_kernel<<<(E + 255) / 256, 256, 0, stream>>>(ei, flags, count, E);
    norm_kernel<<<nb, 256, 0, stream>>>(count, norm, N);
    scan1_kernel<<<nb, 256, 0, stream>>>(count, offsets, bsum, N);
    scan2_kernel<<<1, 512, 0, stream>>>(bsum, nb);
    scan3b_kernel<<<nb, 256, 0, stream>>>(offsets, cursor, bsum, N);
    scatter_kernel<<<(E + 255) / 256, 256, 0, stream>>>(ei, flags, cursor,
                                                        sorted_src, E);

    gemm128_kernel<256, true, false><<<(ND + 127) / 128, 256, 0, stream>>>(
        xd, W1, b1, h, nullptr, nullptr, ND);
    gemm128_kernel<256, true, false><<<(NM + 127) / 128, 256, 0, stream>>>(
        xm, W2, b2, h + (size_t)ND * 128, NM ? nullptr : nullptr, nullptr, NM);
    gemm128_kernel<128, false, true><<<(N + 127) / 128, 256, 0, stream>>>(
        h, Wg, nullptr, h2, h, norm, N);

    {
      long long tt = (long long)N * 32;
      gather_agg_kernel<<<(unsigned)((tt + 255) / 256), 256, 0, stream>>>(
          h2, norm, offsets, count, sorted_src, bg, h, N);
    }
  } else {
    // --- fallback: round-1 atomic path ---
    float* deg = norm;
    init_deg_kernel<<<nb, 256, 0, stream>>>(deg, N);
    deg_kernel<<<(E + 255) / 256, 256, 0, stream>>>(ei, flags, deg, E);
    rsqrt_kernel<<<nb, 256, 0, stream>>>(deg, N);

    gemm128_kernel<256, true, false><<<(ND + 127) / 128, 256, 0, stream>>>(
        xd, W1, b1, h, nullptr, nullptr, ND);
    gemm128_kernel<256, true, false><<<(NM + 127) / 128, 256, 0, stream>>>(
        xm, W2, b2, h + (size_t)ND * 128, nullptr, nullptr, NM);
    gemm128_kernel<128, false, true><<<(N + 127) / 128, 256, 0, stream>>>(
        h, Wg, nullptr, h2, h, deg, N);

    long long tt = (long long)E * 32;
    agg_kernel<<<(unsigned)((tt + 255) / 256), 256, 0, stream>>>(h2, deg, h, ei,
                                                                 flags, E);
    finalize_kernel<<<(N * 32 + 255) / 256, 256, 0, stream>>>(h, bg, N * 32);
  }

  // scores
  {
    long long tt = (long long)ET * 32;
    score_kernel<<<(unsigned)((tt + 255) / 256), 256, 0, stream>>>(h, eit, flags,
                                                                   out, ET);
  }
}

// Round 3
// 443.131 us; speedup vs baseline: 7.1828x; 1.5845x over previous
//
#include <hip/hip_runtime.h>
#include <cstddef>

// ---------------------------------------------------------------------------
// GCNnet round 3: bf16 MFMA GEMMs + bf16 feature tables for gathers.
// Pipeline: hist/scan/scatter (dst-sort) ; W->WT bf16 transpose ;
//   h = relu(X@W+b) via MFMA (bf16 out) ; h2 = h@Wg (bf16 out) ;
//   x2 = relu(gather-agg + self + bg) (bf16) ; scores = dot gathers (fp32).
// ---------------------------------------------------------------------------

typedef __attribute__((ext_vector_type(8))) short short8;
typedef __attribute__((ext_vector_type(4))) float f32x4;

__device__ __forceinline__ unsigned short f2bf(float f) {
  union { float f; unsigned u; } v;
  v.f = f;
  unsigned r = v.u + 0x7fffu + ((v.u >> 16) & 1u);  // RNE
  return (unsigned short)(r >> 16);
}
__device__ __forceinline__ float bf2f(short s) {
  union { unsigned u; float f; } v;
  v.u = ((unsigned)(unsigned short)s) << 16;
  return v.f;
}

__device__ __forceinline__ int eidx(const void* p, int f64, long long i) {
  if (f64) return (int)((const long long*)p)[i];
  return ((const int*)p)[i];
}

// Detect int64 vs int32 edge buffers: values < 2^17, so int64 => odd words 0.
__global__ void detect_kernel(const void* __restrict__ ei,
                              const void* __restrict__ eit,
                              int* __restrict__ flags) {
  const unsigned* a = (const unsigned*)ei;
  const unsigned* b = (const unsigned*)eit;
  int f1 = 1, f2 = 1;
  for (int i = 0; i < 64; ++i) {
    if (a[2 * i + 1] != 0u) f1 = 0;
    if (b[2 * i + 1] != 0u) f2 = 0;
  }
  flags[0] = f1;
  flags[1] = f2;
}

__global__ void hist_kernel(const void* __restrict__ ei,
                            const int* __restrict__ flags,
                            int* __restrict__ count, int E) {
  int e = blockIdx.x * blockDim.x + threadIdx.x;
  if (e >= E) return;
  int d = eidx(ei, flags[0], (long long)E + e);
  atomicAdd(&count[d], 1);
}

__global__ void norm_kernel(const int* __restrict__ count,
                            float* __restrict__ norm, int n) {
  int i = blockIdx.x * blockDim.x + threadIdx.x;
  if (i < n) norm[i] = rsqrtf((float)count[i] + 1.0f);
}

__global__ __launch_bounds__(256) void scan1_kernel(const int* __restrict__ count,
                                                    int* __restrict__ offsets,
                                                    int* __restrict__ bsum, int n) {
  __shared__ int s[256];
  int t = threadIdx.x;
  int i = blockIdx.x * 256 + t;
  int v = (i < n) ? count[i] : 0;
  s[t] = v;
  __syncthreads();
#pragma unroll
  for (int off = 1; off < 256; off <<= 1) {
    int x = (t >= off) ? s[t - off] : 0;
    __syncthreads();
    s[t] += x;
    __syncthreads();
  }
  if (i < n) offsets[i] = s[t] - v;  // exclusive
  if (t == 255) bsum[blockIdx.x] = s[255];
}

__global__ __launch_bounds__(512) void scan2_kernel(int* __restrict__ bsum, int nb) {
  __shared__ int s[512];
  int t = threadIdx.x;
  int v = (t < nb) ? bsum[t] : 0;
  s[t] = v;
  __syncthreads();
#pragma unroll
  for (int off = 1; off < 512; off <<= 1) {
    int x = (t >= off) ? s[t - off] : 0;
    __syncthreads();
    s[t] += x;
    __syncthreads();
  }
  if (t < nb) bsum[t] = s[t] - v;  // exclusive
}

__global__ __launch_bounds__(256) void scan3_kernel(int* __restrict__ offsets,
                                                    int* __restrict__ cursor,
                                                    const int* __restrict__ bsum,
                                                    int n) {
  int i = blockIdx.x * 256 + threadIdx.x;
  if (i < n) {
    int o = offsets[i] + bsum[blockIdx.x];
    offsets[i] = o;
    cursor[i] = o;
  }
}

__global__ void scatter_kernel(const void* __restrict__ ei,
                               const int* __restrict__ flags,
                               int* __restrict__ cursor,
                               int* __restrict__ sorted_src, int E) {
  int e = blockIdx.x * blockDim.x + threadIdx.x;
  if (e >= E) return;
  int f = flags[0];
  int s = eidx(ei, f, e);
  int d = eidx(ei, f, (long long)E + e);
  int pos = atomicAdd(&cursor[d], 1);
  sorted_src[pos] = s;
}

// W[k][n] fp32 (K x 128)  ->  WT[n][k] bf16 (128 x K). One block per n.
__global__ void wtrans_kernel(const float* __restrict__ W,
                              unsigned short* __restrict__ WT, int K) {
  int n = blockIdx.x;
  for (int k = threadIdx.x; k < K; k += blockDim.x)
    WT[(size_t)n * K + k] = f2bf(W[(size_t)k * 128 + n]);
}

// ---------------------------------------------------------------------------
// MFMA GEMM: C[M,128] = X[M,K] @ W[K,128], W given as WT[n][k] bf16.
// Block: 256 thr = 4 waves (2x2), tile 128x128, BK=32.
// RELU: out = relu(C + bias). Output stored bf16.
// v_mfma_f32_16x16x32_bf16: A lane: row=l&15,k=(l>>4)*8+j ; B: col=l&15,same k;
// D: col=l&15, row=(l>>4)*4+r.   [layouts per learn_hip m89/m91/m92]
// ---------------------------------------------------------------------------
template <int K, bool BF16IN, bool RELU>
__global__ __launch_bounds__(256) void mfma_gemm_kernel(
    const void* __restrict__ Xv, const unsigned short* __restrict__ WT,
    const float* __restrict__ bias, unsigned short* __restrict__ Yb, int M) {
  __shared__ short As[128][40];  // 80 B row stride: 2-way bank alias (free)
  __shared__ short Bs[128][40];

  const int tid = threadIdx.x;
  const int lane = tid & 63;
  const int wave = tid >> 6;
  const int wr = wave >> 1, wc = wave & 1;
  const int lrow = lane & 15;
  const int lk = (lane >> 4) * 8;
  const int m0 = blockIdx.x * 128;

  f32x4 acc[4][4];
#pragma unroll
  for (int i = 0; i < 4; ++i)
#pragma unroll
    for (int j = 0; j < 4; ++j) acc[i][j] = (f32x4)(0.0f);

  const int srow = tid >> 1;            // staging row 0..127
  const int skh = (tid & 1) * 16;       // staging k offset 0/16

  for (int k0 = 0; k0 < K; k0 += 32) {
    // ---- stage A (X tile, convert to bf16 if needed) ----
    {
      int grow = m0 + srow;
      short8 p0 = (short8)(0), p1 = (short8)(0);
      if (grow < M) {
        if (BF16IN) {
          const short* Xb = (const short*)Xv;
          p0 = *(const short8*)&Xb[(size_t)grow * K + k0 + skh];
          p1 = *(const short8*)&Xb[(size_t)grow * K + k0 + skh + 8];
        } else {
          const float* Xf = (const float*)Xv;
          const float4* xp = (const float4*)&Xf[(size_t)grow * K + k0 + skh];
          float4 v0 = xp[0], v1 = xp[1], v2 = xp[2], v3 = xp[3];
          p0[0] = (short)f2bf(v0.x); p0[1] = (short)f2bf(v0.y);
          p0[2] = (short)f2bf(v0.z); p0[3] = (short)f2bf(v0.w);
          p0[4] = (short)f2bf(v1.x); p0[5] = (short)f2bf(v1.y);
          p0[6] = (short)f2bf(v1.z); p0[7] = (short)f2bf(v1.w);
          p1[0] = (short)f2bf(v2.x); p1[1] = (short)f2bf(v2.y);
          p1[2] = (short)f2bf(v2.z); p1[3] = (short)f2bf(v2.w);
          p1[4] = (short)f2bf(v3.x); p1[5] = (short)f2bf(v3.y);
          p1[6] = (short)f2bf(v3.z); p1[7] = (short)f2bf(v3.w);
        }
      }
      *(short8*)&As[srow][skh] = p0;
      *(short8*)&As[srow][skh + 8] = p1;
    }
    // ---- stage B (WT tile, already bf16) ----
    {
      const short* wt = (const short*)WT;
      short8 q0 = *(const short8*)&wt[(size_t)srow * K + k0 + skh];
      short8 q1 = *(const short8*)&wt[(size_t)srow * K + k0 + skh + 8];
      *(short8*)&Bs[srow][skh] = q0;
      *(short8*)&Bs[srow][skh + 8] = q1;
    }
    __syncthreads();

    short8 a[4], b[4];
#pragma unroll
    for (int f = 0; f < 4; ++f) {
      a[f] = *(const short8*)&As[wr * 64 + f * 16 + lrow][lk];
      b[f] = *(const short8*)&Bs[wc * 64 + f * 16 + lrow][lk];
    }
#pragma unroll
    for (int fm = 0; fm < 4; ++fm)
#pragma unroll
      for (int fn = 0; fn < 4; ++fn)
        acc[fm][fn] = __builtin_amdgcn_mfma_f32_16x16x32_bf16(
            a[fm], b[fn], acc[fm][fn], 0, 0, 0);
    __syncthreads();
  }

  // ---- epilogue: (optional bias+relu), store bf16 ----
#pragma unroll
  for (int fm = 0; fm < 4; ++fm) {
    int rbase = m0 + wr * 64 + fm * 16 + (lane >> 4) * 4;
#pragma unroll
    for (int fn = 0; fn < 4; ++fn) {
      int col = wc * 64 + fn * 16 + lrow;
      float bv = RELU ? bias[col] : 0.0f;
      f32x4 v = acc[fm][fn];
#pragma unroll
      for (int r = 0; r < 4; ++r) {
        int grow = rbase + r;
        if (grow < M) {
          float x = v[r];
          if (RELU) x = fmaxf(x + bv, 0.0f);
          Yb[(size_t)grow * 128 + col] = f2bf(x);
        }
      }
    }
  }
}

// Gather-aggregate per dst node; 16 lanes/node, 8 ch/lane (bf16 rows).
// x2 = relu(self*norm^2 + sum coef*h2[src] + bg), stored bf16.
__global__ __launch_bounds__(256) void gather_agg_kernel(
    const short* __restrict__ h2, const float* __restrict__ norm,
    const int* __restrict__ offsets, const int* __restrict__ count,
    const int* __restrict__ sorted_src, const float* __restrict__ bg,
    short* __restrict__ x2, int N) {
  int t = blockIdx.x * blockDim.x + threadIdx.x;
  int node = t >> 4;
  if (node >= N) return;
  int l = t & 15;

  float nd = norm[node];
  int start = offsets[node];
  int len = count[node];

  float a[8];
  {
    short8 sv = *(const short8*)&h2[(size_t)node * 128 + l * 8];
    float nw = nd * nd;
#pragma unroll
    for (int i = 0; i < 8; ++i) a[i] = bf2f(sv[i]) * nw;
  }

  int j = 0;
  for (; j + 2 <= len; j += 2) {
    int s0 = sorted_src[start + j];
    int s1 = sorted_src[start + j + 1];
    float c0 = norm[s0] * nd;
    float c1 = norm[s1] * nd;
    short8 v0 = *(const short8*)&h2[(size_t)s0 * 128 + l * 8];
    short8 v1 = *(const short8*)&h2[(size_t)s1 * 128 + l * 8];
#pragma unroll
    for (int i = 0; i < 8; ++i) a[i] += c0 * bf2f(v0[i]) + c1 * bf2f(v1[i]);
  }
  if (j < len) {
    int s0 = sorted_src[start + j];
    float c0 = norm[s0] * nd;
    short8 v0 = *(const short8*)&h2[(size_t)s0 * 128 + l * 8];
#pragma unroll
    for (int i = 0; i < 8; ++i) a[i] += c0 * bf2f(v0[i]);
  }

  short8 o;
#pragma unroll
  for (int i = 0; i < 8; ++i)
    o[i] = (short)f2bf(fmaxf(a[i] + bg[l * 8 + i], 0.0f));
  *(short8*)&x2[(size_t)node * 128 + l * 8] = o;
}

// scores[e] = dot(x2[src], x2[dst]); 16 lanes/edge, 8 ch/lane.
__global__ __launch_bounds__(256) void score_kernel(
    const short* __restrict__ x2, const void* __restrict__ eit,
    const int* __restrict__ flags, float* __restrict__ out, int ET) {
  int t = blockIdx.x * blockDim.x + threadIdx.x;
  int e = t >> 4;
  if (e >= ET) return;
  int l = t & 15;
  int f = flags[1];
  int s = eidx(eit, f, e);
  int d = eidx(eit, f, (long long)ET + e);
  short8 va = *(const short8*)&x2[(size_t)s * 128 + l * 8];
  short8 vb = *(const short8*)&x2[(size_t)d * 128 + l * 8];
  float p = 0.0f;
#pragma unroll
  for (int i = 0; i < 8; ++i) p += bf2f(va[i]) * bf2f(vb[i]);
  p += __shfl_xor(p, 8);
  p += __shfl_xor(p, 4);
  p += __shfl_xor(p, 2);
  p += __shfl_xor(p, 1);
  if (l == 0) out[e] = p;
}

extern "C" void kernel_launch(void* const* d_in, const int* in_sizes, int n_in,
                              void* d_out, int out_size, void* d_ws,
                              size_t ws_size, hipStream_t stream) {
  const float* xd = (const float*)d_in[0];
  const float* xm = (const float*)d_in[1];
  const void* ei = d_in[2];
  const void* eit = d_in[3];
  const float* W1 = (const float*)d_in[4];
  const float* b1 = (const float*)d_in[5];
  const float* W2 = (const float*)d_in[6];
  const float* b2 = (const float*)d_in[7];
  const float* Wg = (const float*)d_in[8];
  const float* bg = (const float*)d_in[9];

  const int ND = in_sizes[0] / 256;
  const int NM = in_sizes[1] / 256;
  const int N = ND + NM;
  const int E = in_sizes[2] / 2;
  const int ET = in_sizes[3] / 2;

  float* out = (float*)d_out;

  // ---- workspace layout ----
  char* p = (char*)d_ws;
  float* norm = (float*)p;        p += (size_t)N * 4;
  int* count = (int*)p;           p += (size_t)N * 4;
  int* offsets = (int*)p;         p += (size_t)N * 4;
  int* cursor = (int*)p;          p += (size_t)N * 4;
  int* bsum = (int*)p;            p += 1024 * 4;
  int* flags = (int*)p;           p += 16 * 4;
  int* sorted_src = (int*)p;      p += (size_t)E * 4;
  p = (char*)(((uintptr_t)p + 15) & ~(uintptr_t)15);
  short* h = (short*)p;           p += (size_t)N * 128 * 2;   // also x2
  short* h2 = (short*)p;          p += (size_t)N * 128 * 2;
  unsigned short* WT1 = (unsigned short*)p; p += 128 * 256 * 2;
  unsigned short* WT2 = (unsigned short*)p; p += 128 * 256 * 2;
  unsigned short* WTg = (unsigned short*)p; p += 128 * 128 * 2;

  const int nb = (N + 255) / 256;

  detect_kernel<<<1, 1, 0, stream>>>(ei, eit, flags);
  hipMemsetAsync(count, 0, (size_t)N * 4, stream);
  hist_kernel<<<(E + 255) / 256, 256, 0, stream>>>(ei, flags, count, E);
  norm_kernel<<<nb, 256, 0, stream>>>(count, norm, N);
  scan1_kernel<<<nb, 256, 0, stream>>>(count, offsets, bsum, N);
  scan2_kernel<<<1, 512, 0, stream>>>(bsum, nb);
  scan3_kernel<<<nb, 256, 0, stream>>>(offsets, cursor, bsum, N);
  scatter_kernel<<<(E + 255) / 256, 256, 0, stream>>>(ei, flags, cursor,
                                                      sorted_src, E);

  wtrans_kernel<<<128, 256, 0, stream>>>(W1, WT1, 256);
  wtrans_kernel<<<128, 256, 0, stream>>>(W2, WT2, 256);
  wtrans_kernel<<<128, 256, 0, stream>>>(Wg, WTg, 128);

  // MLPs -> h (bf16), concat order xd then xm
  mfma_gemm_kernel<256, false, true><<<(ND + 127) / 128, 256, 0, stream>>>(
      xd, WT1, b1, (unsigned short*)h, ND);
  mfma_gemm_kernel<256, false, true><<<(NM + 127) / 128, 256, 0, stream>>>(
      xm, WT2, b2, (unsigned short*)(h + (size_t)ND * 128), NM);
  // GCN matmul: h2 = h @ Wg (bf16 in, bf16 out, no bias/relu)
  mfma_gemm_kernel<128, true, false><<<(N + 127) / 128, 256, 0, stream>>>(
      h, WTg, nullptr, (unsigned short*)h2, N);

  // aggregate + bias + relu -> x2 (reuses h buffer)
  {
    long long tt = (long long)N * 16;
    gather_agg_kernel<<<(unsigned)((tt + 255) / 256), 256, 0, stream>>>(
        h2, norm, offsets, count, sorted_src, bg, h, N);
  }

  // scores
  {
    long long tt = (long long)ET * 16;
    score_kernel<<<(unsigned)((tt + 255) / 256), 256, 0, stream>>>(h, eit, flags,
                                                                   out, ET);
  }
}

// Round 4
// 304.673 us; speedup vs baseline: 10.4470x; 1.4544x over previous
//
#include <hip/hip_runtime.h>
#include <cstddef>

// ---------------------------------------------------------------------------
// GCNnet round 4: replace flat scatter (133 us, 16x write amplification +
// 1.6M device atomics) and hist/scan chain with a two-level bucketed
// counting sort. Buckets = 256-node dst ranges; per-block LDS binning with
// chunk reservation (write-local), then per-bucket LDS node-sort which also
// emits count/offsets/norm. GEMM (bf16 MFMA), gather, score unchanged.
// ---------------------------------------------------------------------------

typedef __attribute__((ext_vector_type(8))) short short8;
typedef __attribute__((ext_vector_type(4))) float f32x4;

#define NBUCK_MAX 2048  // supports node ids < 524288

__device__ __forceinline__ unsigned short f2bf(float f) {
  union { float f; unsigned u; } v;
  v.f = f;
  unsigned r = v.u + 0x7fffu + ((v.u >> 16) & 1u);  // RNE
  return (unsigned short)(r >> 16);
}
__device__ __forceinline__ float bf2f(short s) {
  union { unsigned u; float f; } v;
  v.u = ((unsigned)(unsigned short)s) << 16;
  return v.f;
}

__device__ __forceinline__ int eidx(const void* p, int f64, long long i) {
  if (f64) return (int)((const long long*)p)[i];
  return ((const int*)p)[i];
}

// Detect int64 vs int32 edge buffers: values < 2^17, so int64 => odd words 0.
__global__ void detect_kernel(const void* __restrict__ ei,
                              const void* __restrict__ eit,
                              int* __restrict__ flags) {
  const unsigned* a = (const unsigned*)ei;
  const unsigned* b = (const unsigned*)eit;
  int f1 = 1, f2 = 1;
  for (int i = 0; i < 64; ++i) {
    if (a[2 * i + 1] != 0u) f1 = 0;
    if (b[2 * i + 1] != 0u) f2 = 0;
  }
  flags[0] = f1;
  flags[1] = f2;
}

// LDS-staged histogram of dst buckets (dst>>8).
__global__ __launch_bounds__(256) void bucket_hist_kernel(
    const void* __restrict__ ei, const int* __restrict__ flags,
    int* __restrict__ bcnt, int E, int nbuck) {
  __shared__ int h[NBUCK_MAX];
  for (int i = threadIdx.x; i < nbuck; i += 256) h[i] = 0;
  __syncthreads();
  int f = flags[0];
  int stride = gridDim.x * 256;
  for (long long e = blockIdx.x * 256 + threadIdx.x; e < E; e += stride) {
    int d = eidx(ei, f, (long long)E + e);
    atomicAdd(&h[d >> 8], 1);
  }
  __syncthreads();
  for (int i = threadIdx.x; i < nbuck; i += 256) {
    int c = h[i];
    if (c) atomicAdd(&bcnt[i], c);
  }
}

// Single-block exclusive scan over buckets -> bbase, bcursor.
__global__ __launch_bounds__(1024) void bucket_scan_kernel(
    const int* __restrict__ bcnt, int* __restrict__ bbase,
    int* __restrict__ bcursor, int nbuck) {
  __shared__ int s[1024];
  int t = threadIdx.x;
  int v = (t < nbuck) ? bcnt[t] : 0;
  s[t] = v;
  __syncthreads();
#pragma unroll
  for (int off = 1; off < 1024; off <<= 1) {
    int x = (t >= off) ? s[t - off] : 0;
    __syncthreads();
    s[t] += x;
    __syncthreads();
  }
  if (t < nbuck) {
    int e = s[t] - v;
    bbase[t] = e;
    bcursor[t] = e;
  }
}

// Level-1 binning: each block bins 256*C edges into bucket-contiguous chunks
// of stg[]. Entry = src | (dst&255)<<20.
template <int C>
__global__ __launch_bounds__(256) void bin_kernel(
    const void* __restrict__ ei, const int* __restrict__ flags,
    int* __restrict__ bcursor, int* __restrict__ stg, int E, int nbuck) {
  __shared__ int hcnt[NBUCK_MAX];
  __shared__ int hbase[NBUCK_MAX];
  for (int i = threadIdx.x; i < nbuck; i += 256) hcnt[i] = 0;
  __syncthreads();
  int f = flags[0];
  int pk[C], bk[C];
  long long base = (long long)blockIdx.x * 256 * C;
#pragma unroll
  for (int j = 0; j < C; ++j) {
    long long e = base + j * 256 + threadIdx.x;
    if (e < E) {
      int s = eidx(ei, f, e);
      int d = eidx(ei, f, (long long)E + e);
      bk[j] = d >> 8;
      pk[j] = s | ((d & 255) << 20);
      atomicAdd(&hcnt[bk[j]], 1);
    } else {
      bk[j] = -1;
    }
  }
  __syncthreads();
  for (int i = threadIdx.x; i < nbuck; i += 256) {
    int c = hcnt[i];
    hbase[i] = c ? atomicAdd(&bcursor[i], c) : 0;
    hcnt[i] = 0;
  }
  __syncthreads();
#pragma unroll
  for (int j = 0; j < C; ++j) {
    if (bk[j] >= 0) {
      int r = atomicAdd(&hcnt[bk[j]], 1);
      stg[hbase[bk[j]] + r] = pk[j];
    }
  }
}

// Level-2: one block per bucket. LDS node-hist + scan -> per-node offsets
// (absolute), emit count/offsets/norm, then LDS-cursor scatter of srcs.
__global__ __launch_bounds__(256) void sortfin_kernel(
    const int* __restrict__ stg, const int* __restrict__ bbase,
    const int* __restrict__ bcnt, int* __restrict__ sorted_src,
    int* __restrict__ offsets, int* __restrict__ count,
    float* __restrict__ norm, int N) {
  int b = blockIdx.x;
  int start = bbase[b];
  int len = bcnt[b];
  __shared__ int ncnt[256];
  __shared__ int ncur[256];
  __shared__ int stmp[256];
  int t = threadIdx.x;
  ncnt[t] = 0;
  __syncthreads();
  for (int i = t; i < len; i += 256) {
    int p = stg[start + i];
    atomicAdd(&ncnt[p >> 20], 1);
  }
  __syncthreads();
  int c = ncnt[t];
  stmp[t] = c;
  __syncthreads();
#pragma unroll
  for (int off = 1; off < 256; off <<= 1) {
    int x = (t >= off) ? stmp[t - off] : 0;
    __syncthreads();
    stmp[t] += x;
    __syncthreads();
  }
  int aoff = start + stmp[t] - c;  // absolute exclusive offset
  ncur[t] = aoff;
  int node = (b << 8) + t;
  if (node < N) {
    offsets[node] = aoff;
    count[node] = c;
    norm[node] = rsqrtf((float)c + 1.0f);
  }
  __syncthreads();
  for (int i = t; i < len; i += 256) {
    int p = stg[start + i];
    int pos = atomicAdd(&ncur[p >> 20], 1);
    sorted_src[pos] = p & 0xFFFFF;
  }
}

// W[k][n] fp32 (K x 128)  ->  WT[n][k] bf16 (128 x K). One block per n.
__global__ void wtrans_kernel(const float* __restrict__ W,
                              unsigned short* __restrict__ WT, int K) {
  int n = blockIdx.x;
  for (int k = threadIdx.x; k < K; k += blockDim.x)
    WT[(size_t)n * K + k] = f2bf(W[(size_t)k * 128 + n]);
}

// ---------------------------------------------------------------------------
// MFMA GEMM: C[M,128] = X[M,K] @ W[K,128], W given as WT[n][k] bf16.
// Block: 256 thr = 4 waves (2x2), tile 128x128, BK=32. Output bf16.
// ---------------------------------------------------------------------------
template <int K, bool BF16IN, bool RELU>
__global__ __launch_bounds__(256) void mfma_gemm_kernel(
    const void* __restrict__ Xv, const unsigned short* __restrict__ WT,
    const float* __restrict__ bias, unsigned short* __restrict__ Yb, int M) {
  __shared__ short As[128][40];  // 80 B row stride: 2-way bank alias (free)
  __shared__ short Bs[128][40];

  const int tid = threadIdx.x;
  const int lane = tid & 63;
  const int wave = tid >> 6;
  const int wr = wave >> 1, wc = wave & 1;
  const int lrow = lane & 15;
  const int lk = (lane >> 4) * 8;
  const int m0 = blockIdx.x * 128;

  f32x4 acc[4][4];
#pragma unroll
  for (int i = 0; i < 4; ++i)
#pragma unroll
    for (int j = 0; j < 4; ++j) acc[i][j] = (f32x4)(0.0f);

  const int srow = tid >> 1;       // staging row 0..127
  const int skh = (tid & 1) * 16;  // staging k offset 0/16

  for (int k0 = 0; k0 < K; k0 += 32) {
    {
      int grow = m0 + srow;
      short8 p0 = (short8)(0), p1 = (short8)(0);
      if (grow < M) {
        if (BF16IN) {
          const short* Xb = (const short*)Xv;
          p0 = *(const short8*)&Xb[(size_t)grow * K + k0 + skh];
          p1 = *(const short8*)&Xb[(size_t)grow * K + k0 + skh + 8];
        } else {
          const float* Xf = (const float*)Xv;
          const float4* xp = (const float4*)&Xf[(size_t)grow * K + k0 + skh];
          float4 v0 = xp[0], v1 = xp[1], v2 = xp[2], v3 = xp[3];
          p0[0] = (short)f2bf(v0.x); p0[1] = (short)f2bf(v0.y);
          p0[2] = (short)f2bf(v0.z); p0[3] = (short)f2bf(v0.w);
          p0[4] = (short)f2bf(v1.x); p0[5] = (short)f2bf(v1.y);
          p0[6] = (short)f2bf(v1.z); p0[7] = (short)f2bf(v1.w);
          p1[0] = (short)f2bf(v2.x); p1[1] = (short)f2bf(v2.y);
          p1[2] = (short)f2bf(v2.z); p1[3] = (short)f2bf(v2.w);
          p1[4] = (short)f2bf(v3.x); p1[5] = (short)f2bf(v3.y);
          p1[6] = (short)f2bf(v3.z); p1[7] = (short)f2bf(v3.w);
        }
      }
      *(short8*)&As[srow][skh] = p0;
      *(short8*)&As[srow][skh + 8] = p1;
    }
    {
      const short* wt = (const short*)WT;
      short8 q0 = *(const short8*)&wt[(size_t)srow * K + k0 + skh];
      short8 q1 = *(const short8*)&wt[(size_t)srow * K + k0 + skh + 8];
      *(short8*)&Bs[srow][skh] = q0;
      *(short8*)&Bs[srow][skh + 8] = q1;
    }
    __syncthreads();

    short8 a[4], b[4];
#pragma unroll
    for (int f = 0; f < 4; ++f) {
      a[f] = *(const short8*)&As[wr * 64 + f * 16 + lrow][lk];
      b[f] = *(const short8*)&Bs[wc * 64 + f * 16 + lrow][lk];
    }
#pragma unroll
    for (int fm = 0; fm < 4; ++fm)
#pragma unroll
      for (int fn = 0; fn < 4; ++fn)
        acc[fm][fn] = __builtin_amdgcn_mfma_f32_16x16x32_bf16(
            a[fm], b[fn], acc[fm][fn], 0, 0, 0);
    __syncthreads();
  }

#pragma unroll
  for (int fm = 0; fm < 4; ++fm) {
    int rbase = m0 + wr * 64 + fm * 16 + (lane >> 4) * 4;
#pragma unroll
    for (int fn = 0; fn < 4; ++fn) {
      int col = wc * 64 + fn * 16 + lrow;
      float bv = RELU ? bias[col] : 0.0f;
      f32x4 v = acc[fm][fn];
#pragma unroll
      for (int r = 0; r < 4; ++r) {
        int grow = rbase + r;
        if (grow < M) {
          float x = v[r];
          if (RELU) x = fmaxf(x + bv, 0.0f);
          Yb[(size_t)grow * 128 + col] = f2bf(x);
        }
      }
    }
  }
}

// Gather-aggregate per dst node; 16 lanes/node, 8 ch/lane (bf16 rows).
__global__ __launch_bounds__(256) void gather_agg_kernel(
    const short* __restrict__ h2, const float* __restrict__ norm,
    const int* __restrict__ offsets, const int* __restrict__ count,
    const int* __restrict__ sorted_src, const float* __restrict__ bg,
    short* __restrict__ x2, int N) {
  int t = blockIdx.x * blockDim.x + threadIdx.x;
  int node = t >> 4;
  if (node >= N) return;
  int l = t & 15;

  float nd = norm[node];
  int start = offsets[node];
  int len = count[node];

  float a[8];
  {
    short8 sv = *(const short8*)&h2[(size_t)node * 128 + l * 8];
    float nw = nd * nd;
#pragma unroll
    for (int i = 0; i < 8; ++i) a[i] = bf2f(sv[i]) * nw;
  }

  int j = 0;
  for (; j + 2 <= len; j += 2) {
    int s0 = sorted_src[start + j];
    int s1 = sorted_src[start + j + 1];
    float c0 = norm[s0] * nd;
    float c1 = norm[s1] * nd;
    short8 v0 = *(const short8*)&h2[(size_t)s0 * 128 + l * 8];
    short8 v1 = *(const short8*)&h2[(size_t)s1 * 128 + l * 8];
#pragma unroll
    for (int i = 0; i < 8; ++i) a[i] += c0 * bf2f(v0[i]) + c1 * bf2f(v1[i]);
  }
  if (j < len) {
    int s0 = sorted_src[start + j];
    float c0 = norm[s0] * nd;
    short8 v0 = *(const short8*)&h2[(size_t)s0 * 128 + l * 8];
#pragma unroll
    for (int i = 0; i < 8; ++i) a[i] += c0 * bf2f(v0[i]);
  }

  short8 o;
#pragma unroll
  for (int i = 0; i < 8; ++i)
    o[i] = (short)f2bf(fmaxf(a[i] + bg[l * 8 + i], 0.0f));
  *(short8*)&x2[(size_t)node * 128 + l * 8] = o;
}

// scores[e] = dot(x2[src], x2[dst]); 16 lanes/edge, 8 ch/lane.
__global__ __launch_bounds__(256) void score_kernel(
    const short* __restrict__ x2, const void* __restrict__ eit,
    const int* __restrict__ flags, float* __restrict__ out, int ET) {
  int t = blockIdx.x * blockDim.x + threadIdx.x;
  int e = t >> 4;
  if (e >= ET) return;
  int l = t & 15;
  int f = flags[1];
  int s = eidx(eit, f, e);
  int d = eidx(eit, f, (long long)ET + e);
  short8 va = *(const short8*)&x2[(size_t)s * 128 + l * 8];
  short8 vb = *(const short8*)&x2[(size_t)d * 128 + l * 8];
  float p = 0.0f;
#pragma unroll
  for (int i = 0; i < 8; ++i) p += bf2f(va[i]) * bf2f(vb[i]);
  p += __shfl_xor(p, 8);
  p += __shfl_xor(p, 4);
  p += __shfl_xor(p, 2);
  p += __shfl_xor(p, 1);
  if (l == 0) out[e] = p;
}

extern "C" void kernel_launch(void* const* d_in, const int* in_sizes, int n_in,
                              void* d_out, int out_size, void* d_ws,
                              size_t ws_size, hipStream_t stream) {
  const float* xd = (const float*)d_in[0];
  const float* xm = (const float*)d_in[1];
  const void* ei = d_in[2];
  const void* eit = d_in[3];
  const float* W1 = (const float*)d_in[4];
  const float* b1 = (const float*)d_in[5];
  const float* W2 = (const float*)d_in[6];
  const float* b2 = (const float*)d_in[7];
  const float* Wg = (const float*)d_in[8];
  const float* bg = (const float*)d_in[9];

  const int ND = in_sizes[0] / 256;
  const int NM = in_sizes[1] / 256;
  const int N = ND + NM;
  const int E = in_sizes[2] / 2;
  const int ET = in_sizes[3] / 2;
  const int nbuck = (N + 255) >> 8;

  float* out = (float*)d_out;

  // ---- workspace layout ----
  char* p = (char*)d_ws;
  float* norm = (float*)p;        p += (size_t)N * 4;
  int* count = (int*)p;           p += (size_t)N * 4;
  int* offsets = (int*)p;         p += (size_t)N * 4;
  int* bcnt = (int*)p;            p += NBUCK_MAX * 4;
  int* bbase = (int*)p;           p += NBUCK_MAX * 4;
  int* bcursor = (int*)p;         p += NBUCK_MAX * 4;
  int* flags = (int*)p;           p += 16 * 4;
  int* stg = (int*)p;             p += (size_t)E * 4;
  int* sorted_src = (int*)p;      p += (size_t)E * 4;
  p = (char*)(((uintptr_t)p + 15) & ~(uintptr_t)15);
  short* h = (short*)p;           p += (size_t)N * 128 * 2;  // also x2
  short* h2 = (short*)p;          p += (size_t)N * 128 * 2;
  unsigned short* WT1 = (unsigned short*)p; p += 128 * 256 * 2;
  unsigned short* WT2 = (unsigned short*)p; p += 128 * 256 * 2;
  unsigned short* WTg = (unsigned short*)p; p += 128 * 128 * 2;

  detect_kernel<<<1, 1, 0, stream>>>(ei, eit, flags);
  hipMemsetAsync(bcnt, 0, (size_t)nbuck * 4, stream);

  // ---- two-level counting sort by dst ----
  bucket_hist_kernel<<<256, 256, 0, stream>>>(ei, flags, bcnt, E, nbuck);
  bucket_scan_kernel<<<1, 1024, 0, stream>>>(bcnt, bbase, bcursor, nbuck);
  {
    constexpr int C = 16;
    int nblk = (int)(((long long)E + 256 * C - 1) / (256 * C));
    bin_kernel<C><<<nblk, 256, 0, stream>>>(ei, flags, bcursor, stg, E, nbuck);
  }
  sortfin_kernel<<<nbuck, 256, 0, stream>>>(stg, bbase, bcnt, sorted_src,
                                            offsets, count, norm, N);

  // ---- weights -> bf16 transposed ----
  wtrans_kernel<<<128, 256, 0, stream>>>(W1, WT1, 256);
  wtrans_kernel<<<128, 256, 0, stream>>>(W2, WT2, 256);
  wtrans_kernel<<<128, 256, 0, stream>>>(Wg, WTg, 128);

  // ---- MLPs -> h (bf16), concat order xd then xm ----
  mfma_gemm_kernel<256, false, true><<<(ND + 127) / 128, 256, 0, stream>>>(
      xd, WT1, b1, (unsigned short*)h, ND);
  mfma_gemm_kernel<256, false, true><<<(NM + 127) / 128, 256, 0, stream>>>(
      xm, WT2, b2, (unsigned short*)(h + (size_t)ND * 128), NM);
  // GCN matmul: h2 = h @ Wg
  mfma_gemm_kernel<128, true, false><<<(N + 127) / 128, 256, 0, stream>>>(
      h, WTg, nullptr, (unsigned short*)h2, N);

  // ---- aggregate + bias + relu -> x2 (reuses h buffer) ----
  {
    long long tt = (long long)N * 16;
    gather_agg_kernel<<<(unsigned)((tt + 255) / 256), 256, 0, stream>>>(
        h2, norm, offsets, count, sorted_src, bg, h, N);
  }

  // ---- scores ----
  {
    long long tt = (long long)ET * 16;
    score_kernel<<<(unsigned)((tt + 255) / 256), 256, 0, stream>>>(h, eit, flags,
                                                                   out, ET);
  }
}

// Round 5
// 298.911 us; speedup vs baseline: 10.6483x; 1.0193x over previous
//
#include <hip/hip_runtime.h>
#include <cstddef>

// ---------------------------------------------------------------------------
// GCNnet round 5: MLP (memory-level-parallelism) probe on the two gather
// kernels (8 lanes/row -> 4 outstanding 16B loads per lane), merged MLP
// GEMMs (one predicated launch), merged weight transposes. Sort chain and
// MFMA GEMM structure unchanged.
// ---------------------------------------------------------------------------

typedef __attribute__((ext_vector_type(8))) short short8;
typedef __attribute__((ext_vector_type(4))) float f32x4;

#define NBUCK_MAX 2048  // supports node ids < 524288

__device__ __forceinline__ unsigned short f2bf(float f) {
  union { float f; unsigned u; } v;
  v.f = f;
  unsigned r = v.u + 0x7fffu + ((v.u >> 16) & 1u);  // RNE
  return (unsigned short)(r >> 16);
}
__device__ __forceinline__ float bf2f(short s) {
  union { unsigned u; float f; } v;
  v.u = ((unsigned)(unsigned short)s) << 16;
  return v.f;
}

__device__ __forceinline__ int eidx(const void* p, int f64, long long i) {
  if (f64) return (int)((const long long*)p)[i];
  return ((const int*)p)[i];
}

// Detect int64 vs int32 edge buffers: values < 2^17, so int64 => odd words 0.
__global__ void detect_kernel(const void* __restrict__ ei,
                              const void* __restrict__ eit,
                              int* __restrict__ flags) {
  const unsigned* a = (const unsigned*)ei;
  const unsigned* b = (const unsigned*)eit;
  int f1 = 1, f2 = 1;
  for (int i = 0; i < 64; ++i) {
    if (a[2 * i + 1] != 0u) f1 = 0;
    if (b[2 * i + 1] != 0u) f2 = 0;
  }
  flags[0] = f1;
  flags[1] = f2;
}

// LDS-staged histogram of dst buckets (dst>>8).
__global__ __launch_bounds__(256) void bucket_hist_kernel(
    const void* __restrict__ ei, const int* __restrict__ flags,
    int* __restrict__ bcnt, int E, int nbuck) {
  __shared__ int h[NBUCK_MAX];
  for (int i = threadIdx.x; i < nbuck; i += 256) h[i] = 0;
  __syncthreads();
  int f = flags[0];
  int stride = gridDim.x * 256;
  for (long long e = blockIdx.x * 256 + threadIdx.x; e < E; e += stride) {
    int d = eidx(ei, f, (long long)E + e);
    atomicAdd(&h[d >> 8], 1);
  }
  __syncthreads();
  for (int i = threadIdx.x; i < nbuck; i += 256) {
    int c = h[i];
    if (c) atomicAdd(&bcnt[i], c);
  }
}

// Single-block exclusive scan over buckets -> bbase, bcursor.
__global__ __launch_bounds__(1024) void bucket_scan_kernel(
    const int* __restrict__ bcnt, int* __restrict__ bbase,
    int* __restrict__ bcursor, int nbuck) {
  __shared__ int s[1024];
  int t = threadIdx.x;
  int v = (t < nbuck) ? bcnt[t] : 0;
  s[t] = v;
  __syncthreads();
#pragma unroll
  for (int off = 1; off < 1024; off <<= 1) {
    int x = (t >= off) ? s[t - off] : 0;
    __syncthreads();
    s[t] += x;
    __syncthreads();
  }
  if (t < nbuck) {
    int e = s[t] - v;
    bbase[t] = e;
    bcursor[t] = e;
  }
}

// Level-1 binning: each block bins 256*C edges into bucket-contiguous chunks
// of stg[]. Entry = src | (dst&255)<<20.
template <int C>
__global__ __launch_bounds__(256) void bin_kernel(
    const void* __restrict__ ei, const int* __restrict__ flags,
    int* __restrict__ bcursor, int* __restrict__ stg, int E, int nbuck) {
  __shared__ int hcnt[NBUCK_MAX];
  __shared__ int hbase[NBUCK_MAX];
  for (int i = threadIdx.x; i < nbuck; i += 256) hcnt[i] = 0;
  __syncthreads();
  int f = flags[0];
  int pk[C], bk[C];
  long long base = (long long)blockIdx.x * 256 * C;
#pragma unroll
  for (int j = 0; j < C; ++j) {
    long long e = base + j * 256 + threadIdx.x;
    if (e < E) {
      int s = eidx(ei, f, e);
      int d = eidx(ei, f, (long long)E + e);
      bk[j] = d >> 8;
      pk[j] = s | ((d & 255) << 20);
      atomicAdd(&hcnt[bk[j]], 1);
    } else {
      bk[j] = -1;
    }
  }
  __syncthreads();
  for (int i = threadIdx.x; i < nbuck; i += 256) {
    int c = hcnt[i];
    hbase[i] = c ? atomicAdd(&bcursor[i], c) : 0;
    hcnt[i] = 0;
  }
  __syncthreads();
#pragma unroll
  for (int j = 0; j < C; ++j) {
    if (bk[j] >= 0) {
      int r = atomicAdd(&hcnt[bk[j]], 1);
      stg[hbase[bk[j]] + r] = pk[j];
    }
  }
}

// Level-2: one block per bucket. LDS node-hist + scan -> per-node offsets
// (absolute), emit count/offsets/norm, then LDS-cursor scatter of srcs.
__global__ __launch_bounds__(256) void sortfin_kernel(
    const int* __restrict__ stg, const int* __restrict__ bbase,
    const int* __restrict__ bcnt, int* __restrict__ sorted_src,
    int* __restrict__ offsets, int* __restrict__ count,
    float* __restrict__ norm, int N) {
  int b = blockIdx.x;
  int start = bbase[b];
  int len = bcnt[b];
  __shared__ int ncnt[256];
  __shared__ int ncur[256];
  __shared__ int stmp[256];
  int t = threadIdx.x;
  ncnt[t] = 0;
  __syncthreads();
  for (int i = t; i < len; i += 256) {
    int p = stg[start + i];
    atomicAdd(&ncnt[p >> 20], 1);
  }
  __syncthreads();
  int c = ncnt[t];
  stmp[t] = c;
  __syncthreads();
#pragma unroll
  for (int off = 1; off < 256; off <<= 1) {
    int x = (t >= off) ? stmp[t - off] : 0;
    __syncthreads();
    stmp[t] += x;
    __syncthreads();
  }
  int aoff = start + stmp[t] - c;  // absolute exclusive offset
  ncur[t] = aoff;
  int node = (b << 8) + t;
  if (node < N) {
    offsets[node] = aoff;
    count[node] = c;
    norm[node] = rsqrtf((float)c + 1.0f);
  }
  __syncthreads();
  for (int i = t; i < len; i += 256) {
    int p = stg[start + i];
    int pos = atomicAdd(&ncur[p >> 20], 1);
    sorted_src[pos] = p & 0xFFFFF;
  }
}

// Merged weight transpose: blocks [0,128) W1(K=256), [128,256) W2(K=256),
// [256,384) Wg(K=128).
__global__ void wtrans_all_kernel(const float* __restrict__ W1,
                                  const float* __restrict__ W2,
                                  const float* __restrict__ Wg,
                                  unsigned short* __restrict__ WT1,
                                  unsigned short* __restrict__ WT2,
                                  unsigned short* __restrict__ WTg) {
  int b = blockIdx.x;
  const float* W;
  unsigned short* WT;
  int K, n;
  if (b < 128) {
    W = W1; WT = WT1; K = 256; n = b;
  } else if (b < 256) {
    W = W2; WT = WT2; K = 256; n = b - 128;
  } else {
    W = Wg; WT = WTg; K = 128; n = b - 256;
  }
  for (int k = threadIdx.x; k < K; k += blockDim.x)
    WT[(size_t)n * K + k] = f2bf(W[(size_t)k * 128 + n]);
}

// ---------------------------------------------------------------------------
// MFMA GEMM body (tile 128x128, BK=32, 4 waves 2x2). Shared by both GEMM
// kernels via this inline helper.
// ---------------------------------------------------------------------------
template <int K, bool BF16IN, bool RELU>
__device__ __forceinline__ void gemm_body(const void* __restrict__ Xv,
                                          const unsigned short* __restrict__ WT,
                                          const float* __restrict__ bias,
                                          unsigned short* __restrict__ Yb,
                                          int M, int m0) {
  __shared__ short As[128][40];  // 80 B row stride: 2-way bank alias (free)
  __shared__ short Bs[128][40];

  const int tid = threadIdx.x;
  const int lane = tid & 63;
  const int wave = tid >> 6;
  const int wr = wave >> 1, wc = wave & 1;
  const int lrow = lane & 15;
  const int lk = (lane >> 4) * 8;

  f32x4 acc[4][4];
#pragma unroll
  for (int i = 0; i < 4; ++i)
#pragma unroll
    for (int j = 0; j < 4; ++j) acc[i][j] = (f32x4)(0.0f);

  const int srow = tid >> 1;       // staging row 0..127
  const int skh = (tid & 1) * 16;  // staging k offset 0/16

  for (int k0 = 0; k0 < K; k0 += 32) {
    {
      int grow = m0 + srow;
      short8 p0 = (short8)(0), p1 = (short8)(0);
      if (grow < M) {
        if (BF16IN) {
          const short* Xb = (const short*)Xv;
          p0 = *(const short8*)&Xb[(size_t)grow * K + k0 + skh];
          p1 = *(const short8*)&Xb[(size_t)grow * K + k0 + skh + 8];
        } else {
          const float* Xf = (const float*)Xv;
          const float4* xp = (const float4*)&Xf[(size_t)grow * K + k0 + skh];
          float4 v0 = xp[0], v1 = xp[1], v2 = xp[2], v3 = xp[3];
          p0[0] = (short)f2bf(v0.x); p0[1] = (short)f2bf(v0.y);
          p0[2] = (short)f2bf(v0.z); p0[3] = (short)f2bf(v0.w);
          p0[4] = (short)f2bf(v1.x); p0[5] = (short)f2bf(v1.y);
          p0[6] = (short)f2bf(v1.z); p0[7] = (short)f2bf(v1.w);
          p1[0] = (short)f2bf(v2.x); p1[1] = (short)f2bf(v2.y);
          p1[2] = (short)f2bf(v2.z); p1[3] = (short)f2bf(v2.w);
          p1[4] = (short)f2bf(v3.x); p1[5] = (short)f2bf(v3.y);
          p1[6] = (short)f2bf(v3.z); p1[7] = (short)f2bf(v3.w);
        }
      }
      *(short8*)&As[srow][skh] = p0;
      *(short8*)&As[srow][skh + 8] = p1;
    }
    {
      const short* wt = (const short*)WT;
      short8 q0 = *(const short8*)&wt[(size_t)srow * K + k0 + skh];
      short8 q1 = *(const short8*)&wt[(size_t)srow * K + k0 + skh + 8];
      *(short8*)&Bs[srow][skh] = q0;
      *(short8*)&Bs[srow][skh + 8] = q1;
    }
    __syncthreads();

    short8 a[4], b[4];
#pragma unroll
    for (int f = 0; f < 4; ++f) {
      a[f] = *(const short8*)&As[wr * 64 + f * 16 + lrow][lk];
      b[f] = *(const short8*)&Bs[wc * 64 + f * 16 + lrow][lk];
    }
#pragma unroll
    for (int fm = 0; fm < 4; ++fm)
#pragma unroll
      for (int fn = 0; fn < 4; ++fn)
        acc[fm][fn] = __builtin_amdgcn_mfma_f32_16x16x32_bf16(
            a[fm], b[fn], acc[fm][fn], 0, 0, 0);
    __syncthreads();
  }

#pragma unroll
  for (int fm = 0; fm < 4; ++fm) {
    int rbase = m0 + wr * 64 + fm * 16 + (lane >> 4) * 4;
#pragma unroll
    for (int fn = 0; fn < 4; ++fn) {
      int col = wc * 64 + fn * 16 + lrow;
      float bv = RELU ? bias[col] : 0.0f;
      f32x4 v = acc[fm][fn];
#pragma unroll
      for (int r = 0; r < 4; ++r) {
        int grow = rbase + r;
        if (grow < M) {
          float x = v[r];
          if (RELU) x = fmaxf(x + bv, 0.0f);
          Yb[(size_t)grow * 128 + col] = f2bf(x);
        }
      }
    }
  }
}

// Merged MLP GEMM: blocks [0,nbd) compute xd@W1, blocks [nbd,...) xm@W2.
__global__ __launch_bounds__(256) void mlp_gemm_kernel(
    const float* __restrict__ xd, const float* __restrict__ xm,
    const unsigned short* __restrict__ WT1,
    const unsigned short* __restrict__ WT2, const float* __restrict__ b1,
    const float* __restrict__ b2, unsigned short* __restrict__ h, int ND,
    int NM, int nbd) {
  if ((int)blockIdx.x < nbd) {
    gemm_body<256, false, true>(xd, WT1, b1, h, ND, blockIdx.x * 128);
  } else {
    gemm_body<256, false, true>(xm, WT2, b2, h + (size_t)ND * 128, NM,
                                (blockIdx.x - nbd) * 128);
  }
}

// GCN GEMM: h2 = h @ Wg (bf16 in/out, no bias).
__global__ __launch_bounds__(256) void gcn_gemm_kernel(
    const short* __restrict__ h, const unsigned short* __restrict__ WTg,
    unsigned short* __restrict__ h2, int N) {
  gemm_body<128, true, false>(h, WTg, nullptr, h2, N, blockIdx.x * 128);
}

// Gather-aggregate per dst node; 8 lanes/node, 16 ch/lane, 2 edges in flight.
__global__ __launch_bounds__(256) void gather_agg_kernel(
    const short* __restrict__ h2, const float* __restrict__ norm,
    const int* __restrict__ offsets, const int* __restrict__ count,
    const int* __restrict__ sorted_src, const float* __restrict__ bg,
    short* __restrict__ x2, int N) {
  int t = blockIdx.x * blockDim.x + threadIdx.x;
  int node = t >> 3;
  if (node >= N) return;
  int l = t & 7;

  float nd = norm[node];
  int start = offsets[node];
  int len = count[node];

  float a[16];
  {
    short8 s0 = *(const short8*)&h2[(size_t)node * 128 + l * 16];
    short8 s1 = *(const short8*)&h2[(size_t)node * 128 + l * 16 + 8];
    float nw = nd * nd;
#pragma unroll
    for (int i = 0; i < 8; ++i) {
      a[i] = bf2f(s0[i]) * nw;
      a[8 + i] = bf2f(s1[i]) * nw;
    }
  }

  int j = 0;
  for (; j + 2 <= len; j += 2) {
    int sA = sorted_src[start + j];
    int sB = sorted_src[start + j + 1];
    float cA = norm[sA] * nd;
    float cB = norm[sB] * nd;
    const short* pA = &h2[(size_t)sA * 128 + l * 16];
    const short* pB = &h2[(size_t)sB * 128 + l * 16];
    short8 vA0 = *(const short8*)pA;
    short8 vA1 = *(const short8*)(pA + 8);
    short8 vB0 = *(const short8*)pB;
    short8 vB1 = *(const short8*)(pB + 8);
#pragma unroll
    for (int i = 0; i < 8; ++i) {
      a[i] += cA * bf2f(vA0[i]) + cB * bf2f(vB0[i]);
      a[8 + i] += cA * bf2f(vA1[i]) + cB * bf2f(vB1[i]);
    }
  }
  if (j < len) {
    int sA = sorted_src[start + j];
    float cA = norm[sA] * nd;
    const short* pA = &h2[(size_t)sA * 128 + l * 16];
    short8 vA0 = *(const short8*)pA;
    short8 vA1 = *(const short8*)(pA + 8);
#pragma unroll
    for (int i = 0; i < 8; ++i) {
      a[i] += cA * bf2f(vA0[i]);
      a[8 + i] += cA * bf2f(vA1[i]);
    }
  }

  short8 o0, o1;
#pragma unroll
  for (int i = 0; i < 8; ++i) {
    o0[i] = (short)f2bf(fmaxf(a[i] + bg[l * 16 + i], 0.0f));
    o1[i] = (short)f2bf(fmaxf(a[8 + i] + bg[l * 16 + 8 + i], 0.0f));
  }
  *(short8*)&x2[(size_t)node * 128 + l * 16] = o0;
  *(short8*)&x2[(size_t)node * 128 + l * 16 + 8] = o1;
}

// scores[e] = dot(x2[src], x2[dst]); 8 lanes/edge, 16 ch/lane (4 loads/lane).
__global__ __launch_bounds__(256) void score_kernel(
    const short* __restrict__ x2, const void* __restrict__ eit,
    const int* __restrict__ flags, float* __restrict__ out, int ET) {
  int t = blockIdx.x * blockDim.x + threadIdx.x;
  int e = t >> 3;
  if (e >= ET) return;
  int l = t & 7;
  int f = flags[1];
  int s = eidx(eit, f, e);
  int d = eidx(eit, f, (long long)ET + e);
  const short* pa = &x2[(size_t)s * 128 + l * 16];
  const short* pb = &x2[(size_t)d * 128 + l * 16];
  short8 a0 = *(const short8*)pa;
  short8 a1 = *(const short8*)(pa + 8);
  short8 b0 = *(const short8*)pb;
  short8 b1 = *(const short8*)(pb + 8);
  float p = 0.0f;
#pragma unroll
  for (int i = 0; i < 8; ++i)
    p += bf2f(a0[i]) * bf2f(b0[i]) + bf2f(a1[i]) * bf2f(b1[i]);
  p += __shfl_xor(p, 4);
  p += __shfl_xor(p, 2);
  p += __shfl_xor(p, 1);
  if (l == 0) out[e] = p;
}

extern "C" void kernel_launch(void* const* d_in, const int* in_sizes, int n_in,
                              void* d_out, int out_size, void* d_ws,
                              size_t ws_size, hipStream_t stream) {
  const float* xd = (const float*)d_in[0];
  const float* xm = (const float*)d_in[1];
  const void* ei = d_in[2];
  const void* eit = d_in[3];
  const float* W1 = (const float*)d_in[4];
  const float* b1 = (const float*)d_in[5];
  const float* W2 = (const float*)d_in[6];
  const float* b2 = (const float*)d_in[7];
  const float* Wg = (const float*)d_in[8];
  const float* bg = (const float*)d_in[9];

  const int ND = in_sizes[0] / 256;
  const int NM = in_sizes[1] / 256;
  const int N = ND + NM;
  const int E = in_sizes[2] / 2;
  const int ET = in_sizes[3] / 2;
  const int nbuck = (N + 255) >> 8;

  float* out = (float*)d_out;

  // ---- workspace layout ----
  char* p = (char*)d_ws;
  float* norm = (float*)p;        p += (size_t)N * 4;
  int* count = (int*)p;           p += (size_t)N * 4;
  int* offsets = (int*)p;         p += (size_t)N * 4;
  int* bcnt = (int*)p;            p += NBUCK_MAX * 4;
  int* bbase = (int*)p;           p += NBUCK_MAX * 4;
  int* bcursor = (int*)p;         p += NBUCK_MAX * 4;
  int* flags = (int*)p;           p += 16 * 4;
  int* stg = (int*)p;             p += (size_t)E * 4;
  int* sorted_src = (int*)p;      p += (size_t)E * 4;
  p = (char*)(((uintptr_t)p + 15) & ~(uintptr_t)15);
  short* h = (short*)p;           p += (size_t)N * 128 * 2;  // also x2
  short* h2 = (short*)p;          p += (size_t)N * 128 * 2;
  unsigned short* WT1 = (unsigned short*)p; p += 128 * 256 * 2;
  unsigned short* WT2 = (unsigned short*)p; p += 128 * 256 * 2;
  unsigned short* WTg = (unsigned short*)p; p += 128 * 128 * 2;

  detect_kernel<<<1, 1, 0, stream>>>(ei, eit, flags);
  hipMemsetAsync(bcnt, 0, (size_t)nbuck * 4, stream);

  // ---- two-level counting sort by dst ----
  bucket_hist_kernel<<<256, 256, 0, stream>>>(ei, flags, bcnt, E, nbuck);
  bucket_scan_kernel<<<1, 1024, 0, stream>>>(bcnt, bbase, bcursor, nbuck);
  {
    constexpr int C = 16;
    int nblk = (int)(((long long)E + 256 * C - 1) / (256 * C));
    bin_kernel<C><<<nblk, 256, 0, stream>>>(ei, flags, bcursor, stg, E, nbuck);
  }
  sortfin_kernel<<<nbuck, 256, 0, stream>>>(stg, bbase, bcnt, sorted_src,
                                            offsets, count, norm, N);

  // ---- weights -> bf16 transposed (one launch) ----
  wtrans_all_kernel<<<384, 256, 0, stream>>>(W1, W2, Wg, WT1, WT2, WTg);

  // ---- MLPs -> h (bf16), merged launch ----
  {
    int nbd = (ND + 127) / 128;
    int nbm = (NM + 127) / 128;
    mlp_gemm_kernel<<<nbd + nbm, 256, 0, stream>>>(
        xd, xm, WT1, WT2, b1, b2, (unsigned short*)h, ND, NM, nbd);
  }
  // GCN matmul: h2 = h @ Wg
  gcn_gemm_kernel<<<(N + 127) / 128, 256, 0, stream>>>(
      h, WTg, (unsigned short*)h2, N);

  // ---- aggregate + bias + relu -> x2 (reuses h buffer) ----
  {
    long long tt = (long long)N * 8;
    gather_agg_kernel<<<(unsigned)((tt + 255) / 256), 256, 0, stream>>>(
        h2, norm, offsets, count, sorted_src, bg, h, N);
  }

  // ---- scores ----
  {
    long long tt = (long long)ET * 8;
    score_kernel<<<(unsigned)((tt + 255) / 256), 256, 0, stream>>>(h, eit, flags,
                                                                   out, ET);
  }
}

// Round 6
// 274.524 us; speedup vs baseline: 11.5943x; 1.0888x over previous
//
#include <hip/hip_runtime.h>
#include <cstddef>

// ---------------------------------------------------------------------------
// GCNnet round 6: launch-DAG fusion. Random-gather phases measured at the
// ~3.6 TB/s L2-miss fabric ceiling (round-5 MLP probe: depth made no
// difference), so this round compresses the serialized preprocessing:
//   K0 {detect | wtrans x3 | zero bcnt}
//   K1 {mlp GEMMs (both) | bucket hist}
//   K2 {bucket scan}
//   K3 {gcn GEMM | bin}
//   K4 {sortfin}   K5 {gather_agg}   K6 {score}
// ---------------------------------------------------------------------------

typedef __attribute__((ext_vector_type(8))) short short8;
typedef __attribute__((ext_vector_type(4))) float f32x4;

#define NBUCK_MAX 2048  // supports node ids < 524288

__device__ __forceinline__ unsigned short f2bf(float f) {
  union { float f; unsigned u; } v;
  v.f = f;
  unsigned r = v.u + 0x7fffu + ((v.u >> 16) & 1u);  // RNE
  return (unsigned short)(r >> 16);
}
__device__ __forceinline__ float bf2f(short s) {
  union { unsigned u; float f; } v;
  v.u = ((unsigned)(unsigned short)s) << 16;
  return v.f;
}

__device__ __forceinline__ int eidx(const void* p, int f64, long long i) {
  if (f64) return (int)((const long long*)p)[i];
  return ((const int*)p)[i];
}

// ---------------------------------------------------------------------------
// K0: blocks [0,384) = weight transpose (fp32 W[k][n] -> bf16 WT[n][k]);
//     block 384 = int64/int32 detect + zero bcnt.
// ---------------------------------------------------------------------------
__global__ __launch_bounds__(256) void k0_kernel(
    const float* __restrict__ W1, const float* __restrict__ W2,
    const float* __restrict__ Wg, unsigned short* __restrict__ WT1,
    unsigned short* __restrict__ WT2, unsigned short* __restrict__ WTg,
    const void* __restrict__ ei, const void* __restrict__ eit,
    int* __restrict__ flags, int* __restrict__ bcnt, int nbuck) {
  int b = blockIdx.x;
  int t = threadIdx.x;
  if (b < 384) {
    const float* W;
    unsigned short* WT;
    int K, n;
    if (b < 128) {
      W = W1; WT = WT1; K = 256; n = b;
    } else if (b < 256) {
      W = W2; WT = WT2; K = 256; n = b - 128;
    } else {
      W = Wg; WT = WTg; K = 128; n = b - 256;
    }
    for (int k = t; k < K; k += 256)
      WT[(size_t)n * K + k] = f2bf(W[(size_t)k * 128 + n]);
  } else {
    __shared__ int s1, s2;
    if (t == 0) { s1 = 1; s2 = 1; }
    __syncthreads();
    if (t < 64) {
      if (((const unsigned*)ei)[2 * t + 1] != 0u) s1 = 0;
    } else if (t < 128) {
      if (((const unsigned*)eit)[2 * (t - 64) + 1] != 0u) s2 = 0;
    }
    __syncthreads();
    if (t == 0) { flags[0] = s1; flags[1] = s2; }
    for (int i = t; i < nbuck; i += 256) bcnt[i] = 0;
  }
}

// ---------------------------------------------------------------------------
// MFMA GEMM body (tile 128x128, BK=32, 4 waves 2x2).
// ---------------------------------------------------------------------------
template <int K, bool BF16IN, bool RELU>
__device__ __forceinline__ void gemm_body(const void* __restrict__ Xv,
                                          const unsigned short* __restrict__ WT,
                                          const float* __restrict__ bias,
                                          unsigned short* __restrict__ Yb,
                                          int M, int m0) {
  __shared__ short As[128][40];  // 80 B row stride: 2-way bank alias (free)
  __shared__ short Bs[128][40];

  const int tid = threadIdx.x;
  const int lane = tid & 63;
  const int wave = tid >> 6;
  const int wr = wave >> 1, wc = wave & 1;
  const int lrow = lane & 15;
  const int lk = (lane >> 4) * 8;

  f32x4 acc[4][4];
#pragma unroll
  for (int i = 0; i < 4; ++i)
#pragma unroll
    for (int j = 0; j < 4; ++j) acc[i][j] = (f32x4)(0.0f);

  const int srow = tid >> 1;       // staging row 0..127
  const int skh = (tid & 1) * 16;  // staging k offset 0/16

  for (int k0 = 0; k0 < K; k0 += 32) {
    {
      int grow = m0 + srow;
      short8 p0 = (short8)(0), p1 = (short8)(0);
      if (grow < M) {
        if (BF16IN) {
          const short* Xb = (const short*)Xv;
          p0 = *(const short8*)&Xb[(size_t)grow * K + k0 + skh];
          p1 = *(const short8*)&Xb[(size_t)grow * K + k0 + skh + 8];
        } else {
          const float* Xf = (const float*)Xv;
          const float4* xp = (const float4*)&Xf[(size_t)grow * K + k0 + skh];
          float4 v0 = xp[0], v1 = xp[1], v2 = xp[2], v3 = xp[3];
          p0[0] = (short)f2bf(v0.x); p0[1] = (short)f2bf(v0.y);
          p0[2] = (short)f2bf(v0.z); p0[3] = (short)f2bf(v0.w);
          p0[4] = (short)f2bf(v1.x); p0[5] = (short)f2bf(v1.y);
          p0[6] = (short)f2bf(v1.z); p0[7] = (short)f2bf(v1.w);
          p1[0] = (short)f2bf(v2.x); p1[1] = (short)f2bf(v2.y);
          p1[2] = (short)f2bf(v2.z); p1[3] = (short)f2bf(v2.w);
          p1[4] = (short)f2bf(v3.x); p1[5] = (short)f2bf(v3.y);
          p1[6] = (short)f2bf(v3.z); p1[7] = (short)f2bf(v3.w);
        }
      }
      *(short8*)&As[srow][skh] = p0;
      *(short8*)&As[srow][skh + 8] = p1;
    }
    {
      const short* wt = (const short*)WT;
      short8 q0 = *(const short8*)&wt[(size_t)srow * K + k0 + skh];
      short8 q1 = *(const short8*)&wt[(size_t)srow * K + k0 + skh + 8];
      *(short8*)&Bs[srow][skh] = q0;
      *(short8*)&Bs[srow][skh + 8] = q1;
    }
    __syncthreads();

    short8 a[4], b[4];
#pragma unroll
    for (int f = 0; f < 4; ++f) {
      a[f] = *(const short8*)&As[wr * 64 + f * 16 + lrow][lk];
      b[f] = *(const short8*)&Bs[wc * 64 + f * 16 + lrow][lk];
    }
#pragma unroll
    for (int fm = 0; fm < 4; ++fm)
#pragma unroll
      for (int fn = 0; fn < 4; ++fn)
        acc[fm][fn] = __builtin_amdgcn_mfma_f32_16x16x32_bf16(
            a[fm], b[fn], acc[fm][fn], 0, 0, 0);
    __syncthreads();
  }

#pragma unroll
  for (int fm = 0; fm < 4; ++fm) {
    int rbase = m0 + wr * 64 + fm * 16 + (lane >> 4) * 4;
#pragma unroll
    for (int fn = 0; fn < 4; ++fn) {
      int col = wc * 64 + fn * 16 + lrow;
      float bv = RELU ? bias[col] : 0.0f;
      f32x4 v = acc[fm][fn];
#pragma unroll
      for (int r = 0; r < 4; ++r) {
        int grow = rbase + r;
        if (grow < M) {
          float x = v[r];
          if (RELU) x = fmaxf(x + bv, 0.0f);
          Yb[(size_t)grow * 128 + col] = f2bf(x);
        }
      }
    }
  }
}

// ---------------------------------------------------------------------------
// K1: blocks [0, nbd+nbm) = MLP GEMMs; blocks [nbd+nbm, +256) = bucket hist.
// ---------------------------------------------------------------------------
__global__ __launch_bounds__(256) void k1_kernel(
    const float* __restrict__ xd, const float* __restrict__ xm,
    const unsigned short* __restrict__ WT1,
    const unsigned short* __restrict__ WT2, const float* __restrict__ b1,
    const float* __restrict__ b2, unsigned short* __restrict__ h, int ND,
    int NM, int nbd, int nbm, const void* __restrict__ ei,
    const int* __restrict__ flags, int* __restrict__ bcnt, int E, int nbuck) {
  int b = blockIdx.x;
  int nmlp = nbd + nbm;
  if (b < nbd) {
    gemm_body<256, false, true>(xd, WT1, b1, h, ND, b * 128);
  } else if (b < nmlp) {
    gemm_body<256, false, true>(xm, WT2, b2, h + (size_t)ND * 128, NM,
                                (b - nbd) * 128);
  } else {
    int rb = b - nmlp;  // 0..255
    __shared__ int hsh[NBUCK_MAX];
    for (int i = threadIdx.x; i < nbuck; i += 256) hsh[i] = 0;
    __syncthreads();
    int f = flags[0];
    long long stride = 256LL * 256;
    for (long long e = (long long)rb * 256 + threadIdx.x; e < E; e += stride) {
      int d = eidx(ei, f, (long long)E + e);
      atomicAdd(&hsh[d >> 8], 1);
    }
    __syncthreads();
    for (int i = threadIdx.x; i < nbuck; i += 256) {
      int c = hsh[i];
      if (c) atomicAdd(&bcnt[i], c);
    }
  }
}

// K2: single-block exclusive scan over buckets -> bbase, bcursor.
__global__ __launch_bounds__(1024) void bucket_scan_kernel(
    const int* __restrict__ bcnt, int* __restrict__ bbase,
    int* __restrict__ bcursor, int nbuck) {
  __shared__ int s[1024];
  int t = threadIdx.x;
  int v = (t < nbuck) ? bcnt[t] : 0;
  s[t] = v;
  __syncthreads();
#pragma unroll
  for (int off = 1; off < 1024; off <<= 1) {
    int x = (t >= off) ? s[t - off] : 0;
    __syncthreads();
    s[t] += x;
    __syncthreads();
  }
  if (t < nbuck) {
    int e = s[t] - v;
    bbase[t] = e;
    bcursor[t] = e;
  }
}

// Level-1 binning body: role-local block rb bins 256*C edges into
// bucket-contiguous chunks of stg[]. Entry = src | (dst&255)<<20.
template <int C>
__device__ __forceinline__ void bin_body(const void* __restrict__ ei,
                                         const int* __restrict__ flags,
                                         int* __restrict__ bcursor,
                                         int* __restrict__ stg, int E,
                                         int nbuck, int rb) {
  __shared__ int hcnt[NBUCK_MAX];
  __shared__ int hbase[NBUCK_MAX];
  for (int i = threadIdx.x; i < nbuck; i += 256) hcnt[i] = 0;
  __syncthreads();
  int f = flags[0];
  int pk[C], bk[C];
  long long base = (long long)rb * 256 * C;
#pragma unroll
  for (int j = 0; j < C; ++j) {
    long long e = base + j * 256 + threadIdx.x;
    if (e < E) {
      int s = eidx(ei, f, e);
      int d = eidx(ei, f, (long long)E + e);
      bk[j] = d >> 8;
      pk[j] = s | ((d & 255) << 20);
      atomicAdd(&hcnt[bk[j]], 1);
    } else {
      bk[j] = -1;
    }
  }
  __syncthreads();
  for (int i = threadIdx.x; i < nbuck; i += 256) {
    int c = hcnt[i];
    hbase[i] = c ? atomicAdd(&bcursor[i], c) : 0;
    hcnt[i] = 0;
  }
  __syncthreads();
#pragma unroll
  for (int j = 0; j < C; ++j) {
    if (bk[j] >= 0) {
      int r = atomicAdd(&hcnt[bk[j]], 1);
      stg[hbase[bk[j]] + r] = pk[j];
    }
  }
}

// K3: blocks [0, ngcn) = GCN GEMM (h2 = h @ Wg); blocks [ngcn, +nbin) = bin.
__global__ __launch_bounds__(256) void k3_kernel(
    const short* __restrict__ h, const unsigned short* __restrict__ WTg,
    unsigned short* __restrict__ h2, int N, int ngcn,
    const void* __restrict__ ei, const int* __restrict__ flags,
    int* __restrict__ bcursor, int* __restrict__ stg, int E, int nbuck) {
  int b = blockIdx.x;
  if (b < ngcn) {
    gemm_body<128, true, false>((const void*)h, WTg, nullptr, h2, N, b * 128);
  } else {
    bin_body<16>(ei, flags, bcursor, stg, E, nbuck, b - ngcn);
  }
}

// K4: one block per bucket. LDS node-hist + scan -> absolute per-node
// offsets, emit count/offsets/norm, then LDS-cursor scatter of srcs.
__global__ __launch_bounds__(256) void sortfin_kernel(
    const int* __restrict__ stg, const int* __restrict__ bbase,
    const int* __restrict__ bcnt, int* __restrict__ sorted_src,
    int* __restrict__ offsets, int* __restrict__ count,
    float* __restrict__ norm, int N) {
  int b = blockIdx.x;
  int start = bbase[b];
  int len = bcnt[b];
  __shared__ int ncnt[256];
  __shared__ int ncur[256];
  __shared__ int stmp[256];
  int t = threadIdx.x;
  ncnt[t] = 0;
  __syncthreads();
  for (int i = t; i < len; i += 256) {
    int p = stg[start + i];
    atomicAdd(&ncnt[p >> 20], 1);
  }
  __syncthreads();
  int c = ncnt[t];
  stmp[t] = c;
  __syncthreads();
#pragma unroll
  for (int off = 1; off < 256; off <<= 1) {
    int x = (t >= off) ? stmp[t - off] : 0;
    __syncthreads();
    stmp[t] += x;
    __syncthreads();
  }
  int aoff = start + stmp[t] - c;  // absolute exclusive offset
  ncur[t] = aoff;
  int node = (b << 8) + t;
  if (node < N) {
    offsets[node] = aoff;
    count[node] = c;
    norm[node] = rsqrtf((float)c + 1.0f);
  }
  __syncthreads();
  for (int i = t; i < len; i += 256) {
    int p = stg[start + i];
    int pos = atomicAdd(&ncur[p >> 20], 1);
    sorted_src[pos] = p & 0xFFFFF;
  }
}

// K5: gather-aggregate per dst node; 8 lanes/node, 16 ch/lane, 4-deep unroll.
__global__ __launch_bounds__(256) void gather_agg_kernel(
    const short* __restrict__ h2, const float* __restrict__ norm,
    const int* __restrict__ offsets, const int* __restrict__ count,
    const int* __restrict__ sorted_src, const float* __restrict__ bg,
    short* __restrict__ x2, int N) {
  int t = blockIdx.x * blockDim.x + threadIdx.x;
  int node = t >> 3;
  if (node >= N) return;
  int l = t & 7;

  float nd = norm[node];
  int start = offsets[node];
  int len = count[node];

  float a[16];
  {
    short8 s0 = *(const short8*)&h2[(size_t)node * 128 + l * 16];
    short8 s1 = *(const short8*)&h2[(size_t)node * 128 + l * 16 + 8];
    float nw = nd * nd;
#pragma unroll
    for (int i = 0; i < 8; ++i) {
      a[i] = bf2f(s0[i]) * nw;
      a[8 + i] = bf2f(s1[i]) * nw;
    }
  }

  int j = 0;
  for (; j + 4 <= len; j += 4) {
    int sA = sorted_src[start + j];
    int sB = sorted_src[start + j + 1];
    int sC = sorted_src[start + j + 2];
    int sD = sorted_src[start + j + 3];
    float cA = norm[sA] * nd, cB = norm[sB] * nd;
    float cC = norm[sC] * nd, cD = norm[sD] * nd;
    const short* pA = &h2[(size_t)sA * 128 + l * 16];
    const short* pB = &h2[(size_t)sB * 128 + l * 16];
    const short* pC = &h2[(size_t)sC * 128 + l * 16];
    const short* pD = &h2[(size_t)sD * 128 + l * 16];
    short8 vA0 = *(const short8*)pA, vA1 = *(const short8*)(pA + 8);
    short8 vB0 = *(const short8*)pB, vB1 = *(const short8*)(pB + 8);
    short8 vC0 = *(const short8*)pC, vC1 = *(const short8*)(pC + 8);
    short8 vD0 = *(const short8*)pD, vD1 = *(const short8*)(pD + 8);
#pragma unroll
    for (int i = 0; i < 8; ++i) {
      a[i] += cA * bf2f(vA0[i]) + cB * bf2f(vB0[i]) + cC * bf2f(vC0[i]) +
              cD * bf2f(vD0[i]);
      a[8 + i] += cA * bf2f(vA1[i]) + cB * bf2f(vB1[i]) + cC * bf2f(vC1[i]) +
                  cD * bf2f(vD1[i]);
    }
  }
  for (; j + 2 <= len; j += 2) {
    int sA = sorted_src[start + j];
    int sB = sorted_src[start + j + 1];
    float cA = norm[sA] * nd, cB = norm[sB] * nd;
    const short* pA = &h2[(size_t)sA * 128 + l * 16];
    const short* pB = &h2[(size_t)sB * 128 + l * 16];
    short8 vA0 = *(const short8*)pA, vA1 = *(const short8*)(pA + 8);
    short8 vB0 = *(const short8*)pB, vB1 = *(const short8*)(pB + 8);
#pragma unroll
    for (int i = 0; i < 8; ++i) {
      a[i] += cA * bf2f(vA0[i]) + cB * bf2f(vB0[i]);
      a[8 + i] += cA * bf2f(vA1[i]) + cB * bf2f(vB1[i]);
    }
  }
  if (j < len) {
    int sA = sorted_src[start + j];
    float cA = norm[sA] * nd;
    const short* pA = &h2[(size_t)sA * 128 + l * 16];
    short8 vA0 = *(const short8*)pA, vA1 = *(const short8*)(pA + 8);
#pragma unroll
    for (int i = 0; i < 8; ++i) {
      a[i] += cA * bf2f(vA0[i]);
      a[8 + i] += cA * bf2f(vA1[i]);
    }
  }

  short8 o0, o1;
#pragma unroll
  for (int i = 0; i < 8; ++i) {
    o0[i] = (short)f2bf(fmaxf(a[i] + bg[l * 16 + i], 0.0f));
    o1[i] = (short)f2bf(fmaxf(a[8 + i] + bg[l * 16 + 8 + i], 0.0f));
  }
  *(short8*)&x2[(size_t)node * 128 + l * 16] = o0;
  *(short8*)&x2[(size_t)node * 128 + l * 16 + 8] = o1;
}

// K6: scores[e] = dot(x2[src], x2[dst]); 8 lanes/edge, 16 ch/lane.
__global__ __launch_bounds__(256) void score_kernel(
    const short* __restrict__ x2, const void* __restrict__ eit,
    const int* __restrict__ flags, float* __restrict__ out, int ET) {
  int t = blockIdx.x * blockDim.x + threadIdx.x;
  int e = t >> 3;
  if (e >= ET) return;
  int l = t & 7;
  int f = flags[1];
  int s = eidx(eit, f, e);
  int d = eidx(eit, f, (long long)ET + e);
  const short* pa = &x2[(size_t)s * 128 + l * 16];
  const short* pb = &x2[(size_t)d * 128 + l * 16];
  short8 a0 = *(const short8*)pa;
  short8 a1 = *(const short8*)(pa + 8);
  short8 b0 = *(const short8*)pb;
  short8 b1 = *(const short8*)(pb + 8);
  float p = 0.0f;
#pragma unroll
  for (int i = 0; i < 8; ++i)
    p += bf2f(a0[i]) * bf2f(b0[i]) + bf2f(a1[i]) * bf2f(b1[i]);
  p += __shfl_xor(p, 4);
  p += __shfl_xor(p, 2);
  p += __shfl_xor(p, 1);
  if (l == 0) out[e] = p;
}

extern "C" void kernel_launch(void* const* d_in, const int* in_sizes, int n_in,
                              void* d_out, int out_size, void* d_ws,
                              size_t ws_size, hipStream_t stream) {
  const float* xd = (const float*)d_in[0];
  const float* xm = (const float*)d_in[1];
  const void* ei = d_in[2];
  const void* eit = d_in[3];
  const float* W1 = (const float*)d_in[4];
  const float* b1 = (const float*)d_in[5];
  const float* W2 = (const float*)d_in[6];
  const float* b2 = (const float*)d_in[7];
  const float* Wg = (const float*)d_in[8];
  const float* bg = (const float*)d_in[9];

  const int ND = in_sizes[0] / 256;
  const int NM = in_sizes[1] / 256;
  const int N = ND + NM;
  const int E = in_sizes[2] / 2;
  const int ET = in_sizes[3] / 2;
  const int nbuck = (N + 255) >> 8;

  float* out = (float*)d_out;

  // ---- workspace layout ----
  char* p = (char*)d_ws;
  float* norm = (float*)p;        p += (size_t)N * 4;
  int* count = (int*)p;           p += (size_t)N * 4;
  int* offsets = (int*)p;         p += (size_t)N * 4;
  int* bcnt = (int*)p;            p += NBUCK_MAX * 4;
  int* bbase = (int*)p;           p += NBUCK_MAX * 4;
  int* bcursor = (int*)p;         p += NBUCK_MAX * 4;
  int* flags = (int*)p;           p += 16 * 4;
  int* stg = (int*)p;             p += (size_t)E * 4;
  int* sorted_src = (int*)p;      p += (size_t)E * 4;
  p = (char*)(((uintptr_t)p + 15) & ~(uintptr_t)15);
  short* h = (short*)p;           p += (size_t)N * 128 * 2;  // also x2
  short* h2 = (short*)p;          p += (size_t)N * 128 * 2;
  unsigned short* WT1 = (unsigned short*)p; p += 128 * 256 * 2;
  unsigned short* WT2 = (unsigned short*)p; p += 128 * 256 * 2;
  unsigned short* WTg = (unsigned short*)p; p += 128 * 128 * 2;

  const int nbd = (ND + 127) / 128;
  const int nbm = (NM + 127) / 128;
  const int ngcn = (N + 127) / 128;
  const int nbin = (int)(((long long)E + 4095) / 4096);

  // K0: wtrans x3 | detect | zero bcnt
  k0_kernel<<<385, 256, 0, stream>>>(W1, W2, Wg, WT1, WT2, WTg, ei, eit, flags,
                                     bcnt, nbuck);
  // K1: MLP GEMMs | bucket hist
  k1_kernel<<<nbd + nbm + 256, 256, 0, stream>>>(
      xd, xm, WT1, WT2, b1, b2, (unsigned short*)h, ND, NM, nbd, nbm, ei,
      flags, bcnt, E, nbuck);
  // K2: bucket scan
  bucket_scan_kernel<<<1, 1024, 0, stream>>>(bcnt, bbase, bcursor, nbuck);
  // K3: GCN GEMM | bin
  k3_kernel<<<ngcn + nbin, 256, 0, stream>>>(h, WTg, (unsigned short*)h2, N,
                                             ngcn, ei, flags, bcursor, stg, E,
                                             nbuck);
  // K4: per-bucket node sort + count/offsets/norm
  sortfin_kernel<<<nbuck, 256, 0, stream>>>(stg, bbase, bcnt, sorted_src,
                                            offsets, count, norm, N);
  // K5: aggregate + bias + relu -> x2 (reuses h buffer)
  {
    long long tt = (long long)N * 8;
    gather_agg_kernel<<<(unsigned)((tt + 255) / 256), 256, 0, stream>>>(
        h2, norm, offsets, count, sorted_src, bg, h, N);
  }
  // K6: scores
  {
    long long tt = (long long)ET * 8;
    score_kernel<<<(unsigned)((tt + 255) / 256), 256, 0, stream>>>(h, eit, flags,
                                                                   out, ET);
  }
}